// Round 4
// baseline (2079.243 us; speedup 1.0000x reference)
//
#include <hip/hip_runtime.h>
#include <hip/hip_bf16.h>
#include <math.h>

typedef unsigned short ushort_t;
typedef unsigned int uint_t;

// Problem constants: S=32 scenes, N=32 peds, B=1024, E=64, H=128, PRE=512, MLP_D=1024, T=12
// All float inputs are f32 (round-1 NaN proved it); output is f32 (reference returns f32).
#define T_ 12

// ---- ws layout (float offsets) ----
#define F_LP0   0         // last_pos      (2048)
#define F_LPR   2048      // last_pos_rel  (2048)
#define F_H0    4096      // h0            (131072)
#define F_C0    135168    // c0            (131072)
#define F_WSP   266240    // Wsp (64,2)
#define F_BSP   266368    // bsp (64)
#define F_WIH   266432    // Wih (512,64)
#define F_WHH   299200    // Whh (512,128)
#define F_BIH   364736
#define F_BHH   365248
#define F_WH2P  365760    // (2,128)
#define F_BH2P  366016    // (2)
#define F_WPE   366032    // (64,2)
#define F_BPE   366160    // (64)
#define F_WP1   366224    // (512,192)
#define F_BP1   464528    // (512)
#define F_WP2   465040    // (128,512)
#define F_BP2   530576    // (128)
#define F_WM1   530704    // (1024,256)
#define F_BM1   792848    // (1024)
#define F_WM2   793872    // (128,1024)
#define F_BM2   924944    // (128)
// State / derived:
#define OFF_HC   925072   // carry hidden (B,128)
#define OFF_HL   1056144  // lstm hidden  (B,128)
#define OFF_C    1187216  // cell         (B,128)
#define OFF_X    1318288  // lstm input   (B,64)
#define OFF_LP   1383824  // positions    (B,2)
#define OFF_HP   1385872  // hp = h@Wp1b^T + b512  (B,512)
#define OFF_A2   1910160  // (2,512)
#define OFF_B512 1911184  // (512)
#define OFF_W2Q  1911696  // Wp2 k-packed float4 (512x128)
#define OFF_PHP  1977232  // partial pool max (2,B,128)
// total = 2239376 floats = ~8.96 MB of d_ws

__device__ __forceinline__ float sigf(float x){ return 1.0f/(1.0f+expf(-x)); }

struct Ptrs { const void* p[22]; };

// ---------------- copy all f32 inputs into consolidated ws region ----------------
__global__ __launch_bounds__(256) void k_conv(Ptrs ptrs, float* __restrict__ ws)
{
    const int cums[22] = {0,2048,4096,135168,266240,266368,266432,299200,364736,
                          365248,365760,366016,366018,366146,366210,464514,465026,
                          530562,530690,792834,793858,924930};
    const int dof[22]  = {F_LP0,F_LPR,F_H0,F_C0,F_WSP,F_BSP,F_WIH,F_WHH,F_BIH,F_BHH,
                          F_WH2P,F_BH2P,F_WPE,F_BPE,F_WP1,F_BP1,F_WP2,F_BP2,F_WM1,
                          F_BM1,F_WM2,F_BM2};
    const int TOTAL = 925058;
    int g = blockIdx.x*256 + threadIdx.x;
    if (g < TOTAL) {
        int t = 0;
        #pragma unroll
        for (int i = 1; i < 22; i++) t += (g >= cums[i]);
        int li = g - cums[t];
        ws[dof[t] + li] = ((const float*)ptrs.p[t])[li];
    }
}

// ---------------- init: h,c copy; x0 = lpr@Wsp^T+bsp; lp = last_pos ----------------
__global__ __launch_bounds__(128) void k_init(float* __restrict__ ws)
{
    const int b = blockIdx.x, tid = threadIdx.x;
    ws[OFF_HC + b*128 + tid] = ws[F_H0 + b*128 + tid];
    ws[OFF_C  + b*128 + tid] = ws[F_C0 + b*128 + tid];
    if (tid < 64) {
        float p0 = ws[F_LPR + b*2], p1 = ws[F_LPR + b*2 + 1];
        ws[OFF_X + b*64 + tid] = p0*ws[F_WSP + tid*2] + p1*ws[F_WSP + tid*2+1] + ws[F_BSP + tid];
    }
    if (tid < 2) ws[OFF_LP + b*2 + tid] = ws[F_LP0 + b*2 + tid];
}

// ---------------- A2 = Wpe^T@Wp1a^T (2,512); b512 = bp1 + bpe@Wp1a^T ----------------
__global__ __launch_bounds__(256) void k_pre(float* __restrict__ ws)
{
    const int k = blockIdx.x*256 + threadIdx.x;   // 0..511
    float a0 = 0.f, a1 = 0.f, bb = 0.f;
    for (int e = 0; e < 64; e++) {
        float w = ws[F_WP1 + k*192 + e];
        a0 += ws[F_WPE + e*2 + 0] * w;
        a1 += ws[F_WPE + e*2 + 1] * w;
        bb += ws[F_BPE + e]       * w;
    }
    ws[OFF_A2 + k]       = a0;
    ws[OFF_A2 + 512 + k] = a1;
    ws[OFF_B512 + k]     = bb + ws[F_BP1 + k];
}

// ---------------- pack Wp2^T: W2q[k4*128+m] = float4 of Wp2[m][4k4..4k4+3] ----------------
__global__ __launch_bounds__(256) void k_w2q(float* __restrict__ ws)
{
    const int idx = blockIdx.x*256 + threadIdx.x;  // 0..16383
    const int k4 = idx >> 7, m = idx & 127;
    float4 v = ((const float4*)(ws + F_WP2))[m*128 + k4];
    ((float4*)(ws + OFF_W2Q))[k4*128 + m] = v;
}

// ---------------- LSTM step + rel + cur + next x + out (f32). 4 rows/block ----------------
__global__ __launch_bounds__(128) void k_lstm(float* __restrict__ ws,
                                              float* __restrict__ out, int tstep)
{
    __shared__ float xh[4][192];
    __shared__ float h2s[4][128];
    __shared__ float relsh[4][2];
    const int tid = threadIdx.x;
    const int rb  = blockIdx.x * 4;
    float* X  = ws + OFF_X;  float* HC = ws + OFF_HC; float* C = ws + OFF_C;
    float* HL = ws + OFF_HL; float* LP = ws + OFF_LP;

    #pragma unroll
    for (int r = 0; r < 4; r++) {
        if (tid < 64) xh[r][tid] = X[(rb+r)*64 + tid];
        xh[r][64 + tid] = HC[(rb+r)*128 + tid];
    }
    __syncthreads();

    float gacc[4][4];
    #pragma unroll
    for (int q = 0; q < 4; q++) {
        const int j = tid + q*128;
        const float bias = ws[F_BIH + j] + ws[F_BHH + j];
        float a0 = bias, a1 = bias, a2 = bias, a3 = bias;
        const float4* wi = (const float4*)(ws + F_WIH + j*64);
        #pragma unroll 4
        for (int l = 0; l < 16; l++) {
            float4 w = wi[l]; const int e = 4*l;
            a0 += xh[0][e]*w.x + xh[0][e+1]*w.y + xh[0][e+2]*w.z + xh[0][e+3]*w.w;
            a1 += xh[1][e]*w.x + xh[1][e+1]*w.y + xh[1][e+2]*w.z + xh[1][e+3]*w.w;
            a2 += xh[2][e]*w.x + xh[2][e+1]*w.y + xh[2][e+2]*w.z + xh[2][e+3]*w.w;
            a3 += xh[3][e]*w.x + xh[3][e+1]*w.y + xh[3][e+2]*w.z + xh[3][e+3]*w.w;
        }
        const float4* wh = (const float4*)(ws + F_WHH + j*128);
        #pragma unroll 4
        for (int l = 0; l < 32; l++) {
            float4 w = wh[l]; const int e = 64 + 4*l;
            a0 += xh[0][e]*w.x + xh[0][e+1]*w.y + xh[0][e+2]*w.z + xh[0][e+3]*w.w;
            a1 += xh[1][e]*w.x + xh[1][e+1]*w.y + xh[1][e+2]*w.z + xh[1][e+3]*w.w;
            a2 += xh[2][e]*w.x + xh[2][e+1]*w.y + xh[2][e+2]*w.z + xh[2][e+3]*w.w;
            a3 += xh[3][e]*w.x + xh[3][e+1]*w.y + xh[3][e+2]*w.z + xh[3][e+3]*w.w;
        }
        gacc[q][0]=a0; gacc[q][1]=a1; gacc[q][2]=a2; gacc[q][3]=a3;
    }

    #pragma unroll
    for (int r = 0; r < 4; r++) {
        float i_ = sigf(gacc[0][r]);
        float f_ = sigf(gacc[1][r]);
        float g_ = tanhf(gacc[2][r]);
        float o_ = sigf(gacc[3][r]);
        float c2 = f_ * C[(rb+r)*128 + tid] + i_ * g_;
        float h2 = o_ * tanhf(c2);
        C [(rb+r)*128 + tid] = c2;
        HL[(rb+r)*128 + tid] = h2;
        h2s[r][tid] = h2;
    }
    __syncthreads();

    if (tid < 8) {
        int r = tid >> 1, rr = tid & 1;
        float acc = ws[F_BH2P + rr];
        for (int u = 0; u < 128; u++) acc += h2s[r][u] * ws[F_WH2P + rr*128 + u];
        relsh[r][rr] = acc;
        out[tstep*2048 + (rb+r)*2 + rr] = acc;   // f32 output
        LP[(rb+r)*2 + rr] += acc;                // cur = rel + lp
    }
    __syncthreads();

    if (tid < 64) {
        float w0 = ws[F_WSP + tid*2], w1 = ws[F_WSP + tid*2+1], bb = ws[F_BSP + tid];
        #pragma unroll
        for (int r = 0; r < 4; r++)
            X[(rb+r)*64 + tid] = relsh[r][0]*w0 + relsh[r][1]*w1 + bb;
    }
}

// ---------------- hp[b][k] = hl[b]@Wp1b^T + b512 ----------------
__global__ __launch_bounds__(256) void k_hp(float* __restrict__ ws)
{
    __shared__ float hs[4][128];
    const int tid = threadIdx.x;
    const int rb  = blockIdx.x * 4;
    const float* HL = ws + OFF_HL; float* HP = ws + OFF_HP; const float* B5 = ws + OFF_B512;
    {
        int u = tid & 127, rr = tid >> 7;
        hs[rr][u]   = HL[(rb+rr)*128 + u];
        hs[rr+2][u] = HL[(rb+rr+2)*128 + u];
    }
    __syncthreads();
    for (int kk = tid; kk < 512; kk += 256) {
        const float4* w = (const float4*)(ws + F_WP1 + kk*192 + 64);  // h-columns
        float bb = B5[kk];
        float a0 = bb, a1 = bb, a2 = bb, a3 = bb;
        #pragma unroll 4
        for (int l = 0; l < 32; l++) {
            float4 wv = w[l]; const int e = 4*l;
            a0 += hs[0][e]*wv.x + hs[0][e+1]*wv.y + hs[0][e+2]*wv.z + hs[0][e+3]*wv.w;
            a1 += hs[1][e]*wv.x + hs[1][e+1]*wv.y + hs[1][e+2]*wv.z + hs[1][e+3]*wv.w;
            a2 += hs[2][e]*wv.x + hs[2][e+1]*wv.y + hs[2][e+2]*wv.z + hs[2][e+3]*wv.w;
            a3 += hs[3][e]*wv.x + hs[3][e+1]*wv.y + hs[3][e+2]*wv.z + hs[3][e+3]*wv.w;
        }
        HP[(rb+0)*512 + kk] = a0;
        HP[(rb+1)*512 + kk] = a1;
        HP[(rb+2)*512 + kk] = a2;
        HP[(rb+3)*512 + kk] = a3;
    }
}

// ---------------- fused pool layer 2 + max over j. One block per (scene,i,j-half) ----------------
__global__ __launch_bounds__(256) void k_pool(float* __restrict__ ws)
{
    __shared__ float a1t[512*20];   // [k][jl], stride 20 floats (rows 16B-aligned)
    __shared__ float red[2048];     // [jl][m]
    const int tid = threadIdx.x;
    const int bi = blockIdx.x;
    const int jh = bi & 1;
    const int si = bi >> 1;          // s*32 + i
    const int s  = si >> 5;
    const int m = tid & 127, half = tid >> 7;
    const float* LP = ws + OFF_LP; const float* HP = ws + OFF_HP; const float* A2 = ws + OFF_A2;

    const float c0 = LP[si*2], c1 = LP[si*2 + 1];

    for (int jl = 0; jl < 16; jl++) {
        const int gj = s*32 + jh*16 + jl;
        const float r0 = LP[gj*2] - c0, r1 = LP[gj*2+1] - c1;
        for (int kk = tid; kk < 512; kk += 256) {
            float v = HP[gj*512 + kk] + r0*A2[kk] + r1*A2[512 + kk];
            a1t[kk*20 + jl] = fmaxf(v, 0.0f);
        }
    }
    __syncthreads();

    float acc[16];
    #pragma unroll
    for (int jl = 0; jl < 16; jl++) acc[jl] = 0.0f;

    const float4* W2q4 = (const float4*)(ws + OFF_W2Q);
    const int kbase = half * 256;

#define PSTEP(WK, KO) { const float4* ap = (const float4*)&a1t[(kbase + k4*4 + (KO))*20]; \
    float4 aA=ap[0], aB=ap[1], aC=ap[2], aD=ap[3]; \
    acc[0]+=(WK)*aA.x; acc[1]+=(WK)*aA.y; acc[2]+=(WK)*aA.z; acc[3]+=(WK)*aA.w; \
    acc[4]+=(WK)*aB.x; acc[5]+=(WK)*aB.y; acc[6]+=(WK)*aB.z; acc[7]+=(WK)*aB.w; \
    acc[8]+=(WK)*aC.x; acc[9]+=(WK)*aC.y; acc[10]+=(WK)*aC.z; acc[11]+=(WK)*aC.w; \
    acc[12]+=(WK)*aD.x; acc[13]+=(WK)*aD.y; acc[14]+=(WK)*aD.z; acc[15]+=(WK)*aD.w; }

    for (int k4 = 0; k4 < 64; k4++) {
        const float4 wv = W2q4[(half*64 + k4)*128 + m];
        PSTEP(wv.x, 0) PSTEP(wv.y, 1) PSTEP(wv.z, 2) PSTEP(wv.w, 3)
    }
#undef PSTEP

    if (half == 1) {
        #pragma unroll
        for (int jl = 0; jl < 16; jl++) red[jl*128 + m] = acc[jl];
    }
    __syncthreads();
    if (half == 0) {
        const float bp = ws[F_BP2 + m];
        float mx = 0.0f;   // relu outputs >= 0
        #pragma unroll
        for (int jl = 0; jl < 16; jl++) {
            float v = acc[jl] + red[jl*128 + m] + bp;
            v = fmaxf(v, 0.0f);
            mx = fmaxf(mx, v);
        }
        ws[OFF_PHP + (jh*1024 + si)*128 + m] = mx;
    }
}

// ---------------- post-pool MLP -> refreshed hidden HC. 4 rows/block ----------------
__global__ __launch_bounds__(256) void k_mlp(float* __restrict__ ws)
{
    __shared__ float dh[4][256];
    __shared__ float m1s[4][1024];
    const int tid = threadIdx.x;
    const int rb  = blockIdx.x * 4;
    const float* HL = ws + OFF_HL; const float* PHP = ws + OFF_PHP; float* HC = ws + OFF_HC;

    #pragma unroll
    for (int r = 0; r < 4; r++) {
        if (tid < 128) dh[r][tid] = HL[(rb+r)*128 + tid];
        else {
            int mm = tid - 128;
            dh[r][128 + mm] = fmaxf(PHP[(rb+r)*128 + mm], PHP[(1024 + rb + r)*128 + mm]);
        }
    }
    __syncthreads();

    #pragma unroll
    for (int q = 0; q < 4; q++) {
        const int j = tid + 256*q;
        const float4* w = (const float4*)(ws + F_WM1 + j*256);
        float bb = ws[F_BM1 + j];
        float a0 = bb, a1 = bb, a2 = bb, a3 = bb;
        #pragma unroll 4
        for (int l = 0; l < 64; l++) {
            float4 wv = w[l]; const int e = 4*l;
            float4 d0 = *(const float4*)&dh[0][e];
            float4 d1 = *(const float4*)&dh[1][e];
            float4 d2 = *(const float4*)&dh[2][e];
            float4 d3 = *(const float4*)&dh[3][e];
            a0 += d0.x*wv.x + d0.y*wv.y + d0.z*wv.z + d0.w*wv.w;
            a1 += d1.x*wv.x + d1.y*wv.y + d1.z*wv.z + d1.w*wv.w;
            a2 += d2.x*wv.x + d2.y*wv.y + d2.z*wv.z + d2.w*wv.w;
            a3 += d3.x*wv.x + d3.y*wv.y + d3.z*wv.z + d3.w*wv.w;
        }
        m1s[0][j] = fmaxf(a0, 0.f);
        m1s[1][j] = fmaxf(a1, 0.f);
        m1s[2][j] = fmaxf(a2, 0.f);
        m1s[3][j] = fmaxf(a3, 0.f);
    }
    __syncthreads();

    const int m = tid & 127, half = tid >> 7;
    const float4* w2 = (const float4*)(ws + F_WM2 + m*1024 + half*512);
    float a0 = 0.f, a1 = 0.f, a2 = 0.f, a3 = 0.f;
    #pragma unroll 4
    for (int l = 0; l < 128; l++) {
        float4 wv = w2[l]; const int e = half*512 + 4*l;
        float4 d0 = *(const float4*)&m1s[0][e];
        float4 d1 = *(const float4*)&m1s[1][e];
        float4 d2 = *(const float4*)&m1s[2][e];
        float4 d3 = *(const float4*)&m1s[3][e];
        a0 += d0.x*wv.x + d0.y*wv.y + d0.z*wv.z + d0.w*wv.w;
        a1 += d1.x*wv.x + d1.y*wv.y + d1.z*wv.z + d1.w*wv.w;
        a2 += d2.x*wv.x + d2.y*wv.y + d2.z*wv.z + d2.w*wv.w;
        a3 += d3.x*wv.x + d3.y*wv.y + d3.z*wv.z + d3.w*wv.w;
    }
    if (half == 1) { dh[0][m] = a0; dh[1][m] = a1; dh[2][m] = a2; dh[3][m] = a3; }
    __syncthreads();
    if (half == 0) {
        float bb = ws[F_BM2 + m];
        HC[(rb+0)*128 + m] = fmaxf(a0 + dh[0][m] + bb, 0.f);
        HC[(rb+1)*128 + m] = fmaxf(a1 + dh[1][m] + bb, 0.f);
        HC[(rb+2)*128 + m] = fmaxf(a2 + dh[2][m] + bb, 0.f);
        HC[(rb+3)*128 + m] = fmaxf(a3 + dh[3][m] + bb, 0.f);
    }
}

extern "C" void kernel_launch(void* const* d_in, const int* in_sizes, int n_in,
                              void* d_out, int out_size, void* d_ws, size_t ws_size,
                              hipStream_t stream) {
    float* ws = (float*)d_ws;
    float* out = (float*)d_out;   // reference output dtype is float32

    Ptrs ptrs;   // 22 float tensors, skipping seq_start_end (d_in[4]) and seq_len (d_in[5])
    for (int t = 0; t < 22; t++) ptrs.p[t] = d_in[t < 4 ? t : t + 2];

    k_conv<<<3614, 256, 0, stream>>>(ptrs, ws);   // ceil(925058/256)
    k_init<<<1024, 128, 0, stream>>>(ws);
    k_pre <<<2,    256, 0, stream>>>(ws);
    k_w2q <<<64,   256, 0, stream>>>(ws);

    for (int t = 0; t < T_; t++) {
        k_lstm<<<256, 128, 0, stream>>>(ws, out, t);
        if (t < T_ - 1) {   // last step's pool/MLP would feed a nonexistent step
            k_hp  <<<256,  256, 0, stream>>>(ws);
            k_pool<<<2048, 256, 0, stream>>>(ws);
            k_mlp <<<256,  256, 0, stream>>>(ws);
        }
    }
}

// Round 5
// 1947.630 us; speedup vs baseline: 1.0676x; 1.0676x over previous
//
#include <hip/hip_runtime.h>
#include <hip/hip_bf16.h>
#include <math.h>

typedef unsigned short ushort_t;
typedef unsigned int uint_t;

// Problem constants: S=32 scenes, N=32 peds, B=1024, E=64, H=128, PRE=512, MLP_D=1024, T=12
// All float inputs are f32; output is f32.
#define T_ 12

// ---- ws layout (float offsets) ----
#define F_LP0   0         // last_pos      (2048)
#define F_LPR   2048      // last_pos_rel  (2048)
#define F_H0    4096      // h0            (131072)
#define F_C0    135168    // c0            (131072)
#define F_WSP   266240    // Wsp (64,2)
#define F_BSP   266368    // bsp (64)
#define F_WIH   266432    // Wih (512,64)
#define F_WHH   299200    // Whh (512,128)
#define F_BIH   364736
#define F_BHH   365248
#define F_WH2P  365760    // (2,128)
#define F_BH2P  366016    // (2)
#define F_WPE   366032    // (64,2)
#define F_BPE   366160    // (64)
#define F_WP1   366224    // (512,192)
#define F_BP1   464528    // (512)
#define F_WP2   465040    // (128,512)
#define F_BP2   530576    // (128)
#define F_WM1   530704    // (1024,256)
#define F_BM1   792848    // (1024)
#define F_WM2   793872    // (128,1024)
#define F_BM2   924944    // (128)
// State / derived:
#define OFF_HC   925072   // carry hidden (B,128)
#define OFF_HL   1056144  // lstm hidden  (B,128)
#define OFF_C    1187216  // cell         (B,128)
#define OFF_X    1318288  // lstm input   (B,64)
#define OFF_LP   1383824  // positions    (B,2)
#define OFF_HP   1385872  // hp = h@Wp1b^T + b512  (B,512)
#define OFF_A2   1910160  // (2,512)
#define OFF_B512 1911184  // (512)
#define OFF_W2Q  1911696  // Wp2 k-packed float4 (512x128)
#define OFF_PHP  1977232  // partial pool max (2,B,128)
// total = 2239376 floats = ~8.96 MB of d_ws

__device__ __forceinline__ float sigf(float x){ return 1.0f/(1.0f+expf(-x)); }

struct Ptrs { const void* p[22]; };

// ---------------- copy all f32 inputs into consolidated ws region ----------------
__global__ __launch_bounds__(256) void k_conv(Ptrs ptrs, float* __restrict__ ws)
{
    const int cums[22] = {0,2048,4096,135168,266240,266368,266432,299200,364736,
                          365248,365760,366016,366018,366146,366210,464514,465026,
                          530562,530690,792834,793858,924930};
    const int dof[22]  = {F_LP0,F_LPR,F_H0,F_C0,F_WSP,F_BSP,F_WIH,F_WHH,F_BIH,F_BHH,
                          F_WH2P,F_BH2P,F_WPE,F_BPE,F_WP1,F_BP1,F_WP2,F_BP2,F_WM1,
                          F_BM1,F_WM2,F_BM2};
    const int TOTAL = 925058;
    int g = blockIdx.x*256 + threadIdx.x;
    if (g < TOTAL) {
        int t = 0;
        #pragma unroll
        for (int i = 1; i < 22; i++) t += (g >= cums[i]);
        int li = g - cums[t];
        ws[dof[t] + li] = ((const float*)ptrs.p[t])[li];
    }
}

// ---------------- init: h,c copy; x0 = lpr@Wsp^T+bsp; lp = last_pos ----------------
__global__ __launch_bounds__(128) void k_init(float* __restrict__ ws)
{
    const int b = blockIdx.x, tid = threadIdx.x;
    ws[OFF_HC + b*128 + tid] = ws[F_H0 + b*128 + tid];
    ws[OFF_C  + b*128 + tid] = ws[F_C0 + b*128 + tid];
    if (tid < 64) {
        float p0 = ws[F_LPR + b*2], p1 = ws[F_LPR + b*2 + 1];
        ws[OFF_X + b*64 + tid] = p0*ws[F_WSP + tid*2] + p1*ws[F_WSP + tid*2+1] + ws[F_BSP + tid];
    }
    if (tid < 2) ws[OFF_LP + b*2 + tid] = ws[F_LP0 + b*2 + tid];
}

// ---------------- A2 = Wpe^T@Wp1a^T (2,512); b512 = bp1 + bpe@Wp1a^T ----------------
__global__ __launch_bounds__(256) void k_pre(float* __restrict__ ws)
{
    const int k = blockIdx.x*256 + threadIdx.x;   // 0..511
    float a0 = 0.f, a1 = 0.f, bb = 0.f;
    for (int e = 0; e < 64; e++) {
        float w = ws[F_WP1 + k*192 + e];
        a0 += ws[F_WPE + e*2 + 0] * w;
        a1 += ws[F_WPE + e*2 + 1] * w;
        bb += ws[F_BPE + e]       * w;
    }
    ws[OFF_A2 + k]       = a0;
    ws[OFF_A2 + 512 + k] = a1;
    ws[OFF_B512 + k]     = bb + ws[F_BP1 + k];
}

// ---------------- pack Wp2^T: W2q[k4*128+m] = float4 of Wp2[m][4k4..4k4+3] ----------------
__global__ __launch_bounds__(256) void k_w2q(float* __restrict__ ws)
{
    const int idx = blockIdx.x*256 + threadIdx.x;  // 0..16383
    const int k4 = idx >> 7, m = idx & 127;
    float4 v = ((const float4*)(ws + F_WP2))[m*128 + k4];
    ((float4*)(ws + OFF_W2Q))[k4*128 + m] = v;
}

// ---------------- LSTM step + rel + cur + next x + out (f32). 4 rows/block ----------------
__global__ __launch_bounds__(128) void k_lstm(float* __restrict__ ws,
                                              float* __restrict__ out, int tstep)
{
    __shared__ float xh[4][192];
    __shared__ float h2s[4][128];
    __shared__ float relsh[4][2];
    const int tid = threadIdx.x;
    const int rb  = blockIdx.x * 4;
    float* X  = ws + OFF_X;  float* HC = ws + OFF_HC; float* C = ws + OFF_C;
    float* HL = ws + OFF_HL; float* LP = ws + OFF_LP;

    #pragma unroll
    for (int r = 0; r < 4; r++) {
        if (tid < 64) xh[r][tid] = X[(rb+r)*64 + tid];
        xh[r][64 + tid] = HC[(rb+r)*128 + tid];
    }
    __syncthreads();

    float gacc[4][4];
    #pragma unroll
    for (int q = 0; q < 4; q++) {
        const int j = tid + q*128;
        const float bias = ws[F_BIH + j] + ws[F_BHH + j];
        float a0 = bias, a1 = bias, a2 = bias, a3 = bias;
        const float4* wi = (const float4*)(ws + F_WIH + j*64);
        #pragma unroll 4
        for (int l = 0; l < 16; l++) {
            float4 w = wi[l]; const int e = 4*l;
            a0 += xh[0][e]*w.x + xh[0][e+1]*w.y + xh[0][e+2]*w.z + xh[0][e+3]*w.w;
            a1 += xh[1][e]*w.x + xh[1][e+1]*w.y + xh[1][e+2]*w.z + xh[1][e+3]*w.w;
            a2 += xh[2][e]*w.x + xh[2][e+1]*w.y + xh[2][e+2]*w.z + xh[2][e+3]*w.w;
            a3 += xh[3][e]*w.x + xh[3][e+1]*w.y + xh[3][e+2]*w.z + xh[3][e+3]*w.w;
        }
        const float4* wh = (const float4*)(ws + F_WHH + j*128);
        #pragma unroll 4
        for (int l = 0; l < 32; l++) {
            float4 w = wh[l]; const int e = 64 + 4*l;
            a0 += xh[0][e]*w.x + xh[0][e+1]*w.y + xh[0][e+2]*w.z + xh[0][e+3]*w.w;
            a1 += xh[1][e]*w.x + xh[1][e+1]*w.y + xh[1][e+2]*w.z + xh[1][e+3]*w.w;
            a2 += xh[2][e]*w.x + xh[2][e+1]*w.y + xh[2][e+2]*w.z + xh[2][e+3]*w.w;
            a3 += xh[3][e]*w.x + xh[3][e+1]*w.y + xh[3][e+2]*w.z + xh[3][e+3]*w.w;
        }
        gacc[q][0]=a0; gacc[q][1]=a1; gacc[q][2]=a2; gacc[q][3]=a3;
    }

    #pragma unroll
    for (int r = 0; r < 4; r++) {
        float i_ = sigf(gacc[0][r]);
        float f_ = sigf(gacc[1][r]);
        float g_ = tanhf(gacc[2][r]);
        float o_ = sigf(gacc[3][r]);
        float c2 = f_ * C[(rb+r)*128 + tid] + i_ * g_;
        float h2 = o_ * tanhf(c2);
        C [(rb+r)*128 + tid] = c2;
        HL[(rb+r)*128 + tid] = h2;
        h2s[r][tid] = h2;
    }
    __syncthreads();

    if (tid < 8) {
        int r = tid >> 1, rr = tid & 1;
        float acc = ws[F_BH2P + rr];
        for (int u = 0; u < 128; u++) acc += h2s[r][u] * ws[F_WH2P + rr*128 + u];
        relsh[r][rr] = acc;
        out[tstep*2048 + (rb+r)*2 + rr] = acc;   // f32 output
        LP[(rb+r)*2 + rr] += acc;                // cur = rel + lp
    }
    __syncthreads();

    if (tid < 64) {
        float w0 = ws[F_WSP + tid*2], w1 = ws[F_WSP + tid*2+1], bb = ws[F_BSP + tid];
        #pragma unroll
        for (int r = 0; r < 4; r++)
            X[(rb+r)*64 + tid] = relsh[r][0]*w0 + relsh[r][1]*w1 + bb;
    }
}

// ---------------- hp[b][k] = hl[b]@Wp1b^T + b512 ----------------
__global__ __launch_bounds__(256) void k_hp(float* __restrict__ ws)
{
    __shared__ float hs[4][128];
    const int tid = threadIdx.x;
    const int rb  = blockIdx.x * 4;
    const float* HL = ws + OFF_HL; float* HP = ws + OFF_HP; const float* B5 = ws + OFF_B512;
    {
        int u = tid & 127, rr = tid >> 7;
        hs[rr][u]   = HL[(rb+rr)*128 + u];
        hs[rr+2][u] = HL[(rb+rr+2)*128 + u];
    }
    __syncthreads();
    for (int kk = tid; kk < 512; kk += 256) {
        const float4* w = (const float4*)(ws + F_WP1 + kk*192 + 64);  // h-columns
        float bb = B5[kk];
        float a0 = bb, a1 = bb, a2 = bb, a3 = bb;
        #pragma unroll 4
        for (int l = 0; l < 32; l++) {
            float4 wv = w[l]; const int e = 4*l;
            a0 += hs[0][e]*wv.x + hs[0][e+1]*wv.y + hs[0][e+2]*wv.z + hs[0][e+3]*wv.w;
            a1 += hs[1][e]*wv.x + hs[1][e+1]*wv.y + hs[1][e+2]*wv.z + hs[1][e+3]*wv.w;
            a2 += hs[2][e]*wv.x + hs[2][e+1]*wv.y + hs[2][e+2]*wv.z + hs[2][e+3]*wv.w;
            a3 += hs[3][e]*wv.x + hs[3][e+1]*wv.y + hs[3][e+2]*wv.z + hs[3][e+3]*wv.w;
        }
        HP[(rb+0)*512 + kk] = a0;
        HP[(rb+1)*512 + kk] = a1;
        HP[(rb+2)*512 + kk] = a2;
        HP[(rb+3)*512 + kk] = a3;
    }
}

// ---------------- fused pool layer 2 + max over j. One block per (scene,i,j-half).
// LDS layout [j][k]: phase-1 writes stride-1 (no bank conflicts), phase-2 reads
// wave-uniform (broadcast). Register blocking 8j x 2m -> FMA-bound.
__global__ __launch_bounds__(256) void k_pool(float* __restrict__ ws)
{
    __shared__ float4 a1q[16*128];        // [j][k4]  (16 rows x 512 floats) = 32KB
    __shared__ float  red[2][8][2][64];   // [jq][jj][mi][m6] partial sums (half=1)
    __shared__ float  pmax[2][2][64];     // [jq][mi][m6] per-jq max
    const int tid = threadIdx.x;
    const int bi = blockIdx.x;
    const int jh = bi & 1;
    const int si = bi >> 1;          // s*32 + i
    const int s  = si >> 5;
    const float* LP = ws + OFF_LP;
    const float4* HP4 = (const float4*)(ws + OFF_HP);
    const float4* A2q = (const float4*)(ws + OFF_A2);   // [2][128] float4

    const float c0 = LP[si*2], c1 = LP[si*2 + 1];

    // phase 1: a1[jl][k] = relu(hp[j][k] + r0*A2[0][k] + r1*A2[1][k]), float4-wide
    for (int idx = tid; idx < 16*128; idx += 256) {
        const int jl = idx >> 7, k4 = idx & 127;
        const int gj = s*32 + jh*16 + jl;
        const float r0 = LP[gj*2] - c0, r1 = LP[gj*2+1] - c1;
        float4 hp = HP4[gj*128 + k4];
        float4 a0 = A2q[k4];
        float4 a1v = A2q[128 + k4];
        float4 v;
        v.x = fmaxf(hp.x + r0*a0.x + r1*a1v.x, 0.f);
        v.y = fmaxf(hp.y + r0*a0.y + r1*a1v.y, 0.f);
        v.z = fmaxf(hp.z + r0*a0.z + r1*a1v.z, 0.f);
        v.w = fmaxf(hp.w + r0*a0.w + r1*a1v.w, 0.f);
        a1q[idx] = v;
    }
    __syncthreads();

    // phase 2: thread = (half: k-range, jq: j-octet, m6): 8j x 2m accumulators
    const int m6 = tid & 63, jq = (tid >> 6) & 1, half = tid >> 7;
    float acc[8][2];
    #pragma unroll
    for (int jj = 0; jj < 8; jj++) { acc[jj][0] = 0.f; acc[jj][1] = 0.f; }

    const float4* W2q4 = (const float4*)(ws + OFF_W2Q);
    #pragma unroll 2
    for (int k4 = 0; k4 < 64; k4++) {
        const int kg = half*64 + k4;                 // global float4-index of k
        const float4 w0 = W2q4[kg*128 + m6];
        const float4 w1 = W2q4[kg*128 + m6 + 64];
        #pragma unroll
        for (int jj = 0; jj < 8; jj++) {
            const float4 av = a1q[(jq*8 + jj)*128 + kg];   // wave-uniform broadcast
            acc[jj][0] += av.x*w0.x + av.y*w0.y + av.z*w0.z + av.w*w0.w;
            acc[jj][1] += av.x*w1.x + av.y*w1.y + av.z*w1.z + av.w*w1.w;
        }
    }

    // reduce halves, relu+bias, max over j
    if (half == 1) {
        #pragma unroll
        for (int jj = 0; jj < 8; jj++) {
            red[jq][jj][0][m6] = acc[jj][0];
            red[jq][jj][1][m6] = acc[jj][1];
        }
    }
    __syncthreads();
    if (half == 0) {
        #pragma unroll
        for (int mi = 0; mi < 2; mi++) {
            const float bp = ws[F_BP2 + mi*64 + m6];
            float mx = 0.0f;   // relu outputs >= 0
            #pragma unroll
            for (int jj = 0; jj < 8; jj++) {
                float v = acc[jj][mi] + red[jq][jj][mi][m6] + bp;
                mx = fmaxf(mx, fmaxf(v, 0.f));
            }
            pmax[jq][mi][m6] = mx;
        }
    }
    __syncthreads();
    if (tid < 64) {
        #pragma unroll
        for (int mi = 0; mi < 2; mi++) {
            float mx = fmaxf(pmax[0][mi][m6], pmax[1][mi][m6]);
            ws[OFF_PHP + (jh*1024 + si)*128 + mi*64 + m6] = mx;
        }
    }
}

// ---------------- post-pool MLP -> refreshed hidden HC. 4 rows/block ----------------
__global__ __launch_bounds__(256) void k_mlp(float* __restrict__ ws)
{
    __shared__ float dh[4][256];
    __shared__ float m1s[4][1024];
    const int tid = threadIdx.x;
    const int rb  = blockIdx.x * 4;
    const float* HL = ws + OFF_HL; const float* PHP = ws + OFF_PHP; float* HC = ws + OFF_HC;

    #pragma unroll
    for (int r = 0; r < 4; r++) {
        if (tid < 128) dh[r][tid] = HL[(rb+r)*128 + tid];
        else {
            int mm = tid - 128;
            dh[r][128 + mm] = fmaxf(PHP[(rb+r)*128 + mm], PHP[(1024 + rb + r)*128 + mm]);
        }
    }
    __syncthreads();

    #pragma unroll
    for (int q = 0; q < 4; q++) {
        const int j = tid + 256*q;
        const float4* w = (const float4*)(ws + F_WM1 + j*256);
        float bb = ws[F_BM1 + j];
        float a0 = bb, a1 = bb, a2 = bb, a3 = bb;
        #pragma unroll 4
        for (int l = 0; l < 64; l++) {
            float4 wv = w[l]; const int e = 4*l;
            float4 d0 = *(const float4*)&dh[0][e];
            float4 d1 = *(const float4*)&dh[1][e];
            float4 d2 = *(const float4*)&dh[2][e];
            float4 d3 = *(const float4*)&dh[3][e];
            a0 += d0.x*wv.x + d0.y*wv.y + d0.z*wv.z + d0.w*wv.w;
            a1 += d1.x*wv.x + d1.y*wv.y + d1.z*wv.z + d1.w*wv.w;
            a2 += d2.x*wv.x + d2.y*wv.y + d2.z*wv.z + d2.w*wv.w;
            a3 += d3.x*wv.x + d3.y*wv.y + d3.z*wv.z + d3.w*wv.w;
        }
        m1s[0][j] = fmaxf(a0, 0.f);
        m1s[1][j] = fmaxf(a1, 0.f);
        m1s[2][j] = fmaxf(a2, 0.f);
        m1s[3][j] = fmaxf(a3, 0.f);
    }
    __syncthreads();

    const int m = tid & 127, half = tid >> 7;
    const float4* w2 = (const float4*)(ws + F_WM2 + m*1024 + half*512);
    float a0 = 0.f, a1 = 0.f, a2 = 0.f, a3 = 0.f;
    #pragma unroll 4
    for (int l = 0; l < 128; l++) {
        float4 wv = w2[l]; const int e = half*512 + 4*l;
        float4 d0 = *(const float4*)&m1s[0][e];
        float4 d1 = *(const float4*)&m1s[1][e];
        float4 d2 = *(const float4*)&m1s[2][e];
        float4 d3 = *(const float4*)&m1s[3][e];
        a0 += d0.x*wv.x + d0.y*wv.y + d0.z*wv.z + d0.w*wv.w;
        a1 += d1.x*wv.x + d1.y*wv.y + d1.z*wv.z + d1.w*wv.w;
        a2 += d2.x*wv.x + d2.y*wv.y + d2.z*wv.z + d2.w*wv.w;
        a3 += d3.x*wv.x + d3.y*wv.y + d3.z*wv.z + d3.w*wv.w;
    }
    if (half == 1) { dh[0][m] = a0; dh[1][m] = a1; dh[2][m] = a2; dh[3][m] = a3; }
    __syncthreads();
    if (half == 0) {
        float bb = ws[F_BM2 + m];
        HC[(rb+0)*128 + m] = fmaxf(a0 + dh[0][m] + bb, 0.f);
        HC[(rb+1)*128 + m] = fmaxf(a1 + dh[1][m] + bb, 0.f);
        HC[(rb+2)*128 + m] = fmaxf(a2 + dh[2][m] + bb, 0.f);
        HC[(rb+3)*128 + m] = fmaxf(a3 + dh[3][m] + bb, 0.f);
    }
}

extern "C" void kernel_launch(void* const* d_in, const int* in_sizes, int n_in,
                              void* d_out, int out_size, void* d_ws, size_t ws_size,
                              hipStream_t stream) {
    float* ws = (float*)d_ws;
    float* out = (float*)d_out;   // reference output dtype is float32

    Ptrs ptrs;   // 22 float tensors, skipping seq_start_end (d_in[4]) and seq_len (d_in[5])
    for (int t = 0; t < 22; t++) ptrs.p[t] = d_in[t < 4 ? t : t + 2];

    k_conv<<<3614, 256, 0, stream>>>(ptrs, ws);   // ceil(925058/256)
    k_init<<<1024, 128, 0, stream>>>(ws);
    k_pre <<<2,    256, 0, stream>>>(ws);
    k_w2q <<<64,   256, 0, stream>>>(ws);

    for (int t = 0; t < T_; t++) {
        k_lstm<<<256, 128, 0, stream>>>(ws, out, t);
        if (t < T_ - 1) {   // last step's pool/MLP would feed a nonexistent step
            k_hp  <<<256,  256, 0, stream>>>(ws);
            k_pool<<<2048, 256, 0, stream>>>(ws);
            k_mlp <<<256,  256, 0, stream>>>(ws);
        }
    }
}

// Round 6
// 1322.403 us; speedup vs baseline: 1.5723x; 1.4728x over previous
//
#include <hip/hip_runtime.h>
#include <hip/hip_bf16.h>
#include <math.h>

typedef unsigned short ushort_t;
typedef unsigned int uint_t;

// Problem constants: S=32 scenes, N=32 peds, B=1024, E=64, H=128, PRE=512, MLP_D=1024, T=12
// All float inputs are f32; output is f32.
#define T_ 12

// ---- ws layout (float offsets) ----
#define F_LP0   0         // last_pos      (2048)
#define F_LPR   2048      // last_pos_rel  (2048)
#define F_H0    4096      // h0            (131072)
#define F_C0    135168    // c0            (131072)
#define F_WSP   266240    // Wsp (64,2)
#define F_BSP   266368    // bsp (64)
#define F_WIH   266432    // Wih (512,64)
#define F_WHH   299200    // Whh (512,128)
#define F_BIH   364736
#define F_BHH   365248
#define F_WH2P  365760    // (2,128)
#define F_BH2P  366016    // (2)
#define F_WPE   366032    // (64,2)
#define F_BPE   366160    // (64)
#define F_WP1   366224    // (512,192)
#define F_BP1   464528    // (512)
#define F_WP2   465040    // (128,512)
#define F_BP2   530576    // (128)
#define F_WM1   530704    // (1024,256)
#define F_BM1   792848    // (1024)
#define F_WM2   793872    // (128,1024)
#define F_BM2   924944    // (128)
// State / derived:
#define OFF_HC   925072   // carry hidden (B,128)
#define OFF_HL   1056144  // lstm hidden  (B,128)
#define OFF_C    1187216  // cell         (B,128)
#define OFF_X    1318288  // lstm input   (B,64)
#define OFF_LP   1383824  // positions    (B,2)
#define OFF_HP   1385872  // hp = h@Wp1b^T + b512  (B,512)
#define OFF_A2   1910160  // (2,512)
#define OFF_B512 1911184  // (512)
#define OFF_W2F  1911696  // Wp2 bf16 B-fragment-packed (65536 ushorts = 32768 uints)
#define OFF_PHP  1977232  // pool max output (B,128)
// total ~2 M floats = ~8.2 MB of d_ws

typedef __attribute__((ext_vector_type(8))) short short8v;   // 8 bf16 (4 VGPRs)
typedef __attribute__((ext_vector_type(4))) float f32x4;

__device__ __forceinline__ float sigf(float x){ return 1.0f/(1.0f+expf(-x)); }
__device__ __forceinline__ uint_t f2b(float f){  // RNE f32->bf16 (bits in low 16)
    uint_t u = __float_as_uint(f);
    return (u + 0x7FFFu + ((u >> 16) & 1u)) >> 16;
}

struct Ptrs { const void* p[22]; };

// ---------------- copy all f32 inputs into consolidated ws region ----------------
__global__ __launch_bounds__(256) void k_conv(Ptrs ptrs, float* __restrict__ ws)
{
    const int cums[22] = {0,2048,4096,135168,266240,266368,266432,299200,364736,
                          365248,365760,366016,366018,366146,366210,464514,465026,
                          530562,530690,792834,793858,924930};
    const int dof[22]  = {F_LP0,F_LPR,F_H0,F_C0,F_WSP,F_BSP,F_WIH,F_WHH,F_BIH,F_BHH,
                          F_WH2P,F_BH2P,F_WPE,F_BPE,F_WP1,F_BP1,F_WP2,F_BP2,F_WM1,
                          F_BM1,F_WM2,F_BM2};
    const int TOTAL = 925058;
    int g = blockIdx.x*256 + threadIdx.x;
    if (g < TOTAL) {
        int t = 0;
        #pragma unroll
        for (int i = 1; i < 22; i++) t += (g >= cums[i]);
        int li = g - cums[t];
        ws[dof[t] + li] = ((const float*)ptrs.p[t])[li];
    }
}

// ---------------- init: h,c copy; x0 = lpr@Wsp^T+bsp; lp = last_pos ----------------
__global__ __launch_bounds__(128) void k_init(float* __restrict__ ws)
{
    const int b = blockIdx.x, tid = threadIdx.x;
    ws[OFF_HC + b*128 + tid] = ws[F_H0 + b*128 + tid];
    ws[OFF_C  + b*128 + tid] = ws[F_C0 + b*128 + tid];
    if (tid < 64) {
        float p0 = ws[F_LPR + b*2], p1 = ws[F_LPR + b*2 + 1];
        ws[OFF_X + b*64 + tid] = p0*ws[F_WSP + tid*2] + p1*ws[F_WSP + tid*2+1] + ws[F_BSP + tid];
    }
    if (tid < 2) ws[OFF_LP + b*2 + tid] = ws[F_LP0 + b*2 + tid];
}

// ---------------- A2 = Wpe^T@Wp1a^T (2,512); b512 = bp1 + bpe@Wp1a^T ----------------
__global__ __launch_bounds__(256) void k_pre(float* __restrict__ ws)
{
    const int k = blockIdx.x*256 + threadIdx.x;   // 0..511
    float a0 = 0.f, a1 = 0.f, bb = 0.f;
    for (int e = 0; e < 64; e++) {
        float w = ws[F_WP1 + k*192 + e];
        a0 += ws[F_WPE + e*2 + 0] * w;
        a1 += ws[F_WPE + e*2 + 1] * w;
        bb += ws[F_BPE + e]       * w;
    }
    ws[OFF_A2 + k]       = a0;
    ws[OFF_A2 + 512 + k] = a1;
    ws[OFF_B512 + k]     = bb + ws[F_BP1 + k];
}

// ---------------- pack Wp2 into bf16 MFMA B-fragment order ----------------
// W2F[(((mt*16+kk)*64 + lane)*8 + i] = bf16(Wp2[col][k]), col=mt*16+(lane&15),
// k = kk*32 + (lane>>4)*8 + i  (B-frag for mfma_f32_16x16x32_bf16)
__global__ __launch_bounds__(256) void k_w2f(float* __restrict__ ws)
{
    const int idx = blockIdx.x*256 + threadIdx.x;  // 0..65535
    const int i = idx & 7, lane = (idx >> 3) & 63, kk = (idx >> 9) & 15, mt = idx >> 13;
    const int col = mt*16 + (lane & 15);
    const int k   = kk*32 + ((lane >> 4) << 3) + i;
    ushort_t* w2f = (ushort_t*)(ws + OFF_W2F);
    w2f[idx] = (ushort_t)f2b(ws[F_WP2 + col*512 + k]);
}

// ---------------- LSTM step + rel + cur + next x + out (f32). 4 rows/block ----------------
__global__ __launch_bounds__(128) void k_lstm(float* __restrict__ ws,
                                              float* __restrict__ out, int tstep)
{
    __shared__ float xh[4][192];
    __shared__ float h2s[4][128];
    __shared__ float relsh[4][2];
    const int tid = threadIdx.x;
    const int rb  = blockIdx.x * 4;
    float* X  = ws + OFF_X;  float* HC = ws + OFF_HC; float* C = ws + OFF_C;
    float* HL = ws + OFF_HL; float* LP = ws + OFF_LP;

    #pragma unroll
    for (int r = 0; r < 4; r++) {
        if (tid < 64) xh[r][tid] = X[(rb+r)*64 + tid];
        xh[r][64 + tid] = HC[(rb+r)*128 + tid];
    }
    __syncthreads();

    float gacc[4][4];
    #pragma unroll
    for (int q = 0; q < 4; q++) {
        const int j = tid + q*128;
        const float bias = ws[F_BIH + j] + ws[F_BHH + j];
        float a0 = bias, a1 = bias, a2 = bias, a3 = bias;
        const float4* wi = (const float4*)(ws + F_WIH + j*64);
        #pragma unroll 4
        for (int l = 0; l < 16; l++) {
            float4 w = wi[l]; const int e = 4*l;
            a0 += xh[0][e]*w.x + xh[0][e+1]*w.y + xh[0][e+2]*w.z + xh[0][e+3]*w.w;
            a1 += xh[1][e]*w.x + xh[1][e+1]*w.y + xh[1][e+2]*w.z + xh[1][e+3]*w.w;
            a2 += xh[2][e]*w.x + xh[2][e+1]*w.y + xh[2][e+2]*w.z + xh[2][e+3]*w.w;
            a3 += xh[3][e]*w.x + xh[3][e+1]*w.y + xh[3][e+2]*w.z + xh[3][e+3]*w.w;
        }
        const float4* wh = (const float4*)(ws + F_WHH + j*128);
        #pragma unroll 4
        for (int l = 0; l < 32; l++) {
            float4 w = wh[l]; const int e = 64 + 4*l;
            a0 += xh[0][e]*w.x + xh[0][e+1]*w.y + xh[0][e+2]*w.z + xh[0][e+3]*w.w;
            a1 += xh[1][e]*w.x + xh[1][e+1]*w.y + xh[1][e+2]*w.z + xh[1][e+3]*w.w;
            a2 += xh[2][e]*w.x + xh[2][e+1]*w.y + xh[2][e+2]*w.z + xh[2][e+3]*w.w;
            a3 += xh[3][e]*w.x + xh[3][e+1]*w.y + xh[3][e+2]*w.z + xh[3][e+3]*w.w;
        }
        gacc[q][0]=a0; gacc[q][1]=a1; gacc[q][2]=a2; gacc[q][3]=a3;
    }

    #pragma unroll
    for (int r = 0; r < 4; r++) {
        float i_ = sigf(gacc[0][r]);
        float f_ = sigf(gacc[1][r]);
        float g_ = tanhf(gacc[2][r]);
        float o_ = sigf(gacc[3][r]);
        float c2 = f_ * C[(rb+r)*128 + tid] + i_ * g_;
        float h2 = o_ * tanhf(c2);
        C [(rb+r)*128 + tid] = c2;
        HL[(rb+r)*128 + tid] = h2;
        h2s[r][tid] = h2;
    }
    __syncthreads();

    if (tid < 8) {
        int r = tid >> 1, rr = tid & 1;
        float acc = ws[F_BH2P + rr];
        for (int u = 0; u < 128; u++) acc += h2s[r][u] * ws[F_WH2P + rr*128 + u];
        relsh[r][rr] = acc;
        out[tstep*2048 + (rb+r)*2 + rr] = acc;   // f32 output
        LP[(rb+r)*2 + rr] += acc;                // cur = rel + lp
    }
    __syncthreads();

    if (tid < 64) {
        float w0 = ws[F_WSP + tid*2], w1 = ws[F_WSP + tid*2+1], bb = ws[F_BSP + tid];
        #pragma unroll
        for (int r = 0; r < 4; r++)
            X[(rb+r)*64 + tid] = relsh[r][0]*w0 + relsh[r][1]*w1 + bb;
    }
}

// ---------------- hp[b][k] = hl[b]@Wp1b^T + b512 ----------------
__global__ __launch_bounds__(256) void k_hp(float* __restrict__ ws)
{
    __shared__ float hs[4][128];
    const int tid = threadIdx.x;
    const int rb  = blockIdx.x * 4;
    const float* HL = ws + OFF_HL; float* HP = ws + OFF_HP; const float* B5 = ws + OFF_B512;
    {
        int u = tid & 127, rr = tid >> 7;
        hs[rr][u]   = HL[(rb+rr)*128 + u];
        hs[rr+2][u] = HL[(rb+rr+2)*128 + u];
    }
    __syncthreads();
    for (int kk = tid; kk < 512; kk += 256) {
        const float4* w = (const float4*)(ws + F_WP1 + kk*192 + 64);  // h-columns
        float bb = B5[kk];
        float a0 = bb, a1 = bb, a2 = bb, a3 = bb;
        #pragma unroll 4
        for (int l = 0; l < 32; l++) {
            float4 wv = w[l]; const int e = 4*l;
            a0 += hs[0][e]*wv.x + hs[0][e+1]*wv.y + hs[0][e+2]*wv.z + hs[0][e+3]*wv.w;
            a1 += hs[1][e]*wv.x + hs[1][e+1]*wv.y + hs[1][e+2]*wv.z + hs[1][e+3]*wv.w;
            a2 += hs[2][e]*wv.x + hs[2][e+1]*wv.y + hs[2][e+2]*wv.z + hs[2][e+3]*wv.w;
            a3 += hs[3][e]*wv.x + hs[3][e+1]*wv.y + hs[3][e+2]*wv.z + hs[3][e+3]*wv.w;
        }
        HP[(rb+0)*512 + kk] = a0;
        HP[(rb+1)*512 + kk] = a1;
        HP[(rb+2)*512 + kk] = a2;
        HP[(rb+3)*512 + kk] = a3;
    }
}

// ---------------- MFMA pool layer-2 + max over j. One block per (scene,i).
// Phase 1: a1[j][k] = relu(hp[j][k]+r0*A2[0][k]+r1*A2[1][k]) -> bf16 in swizzled LDS.
// Phase 2: C[32j x 128m] = a1 @ W2 via mfma_f32_16x16x32_bf16; relu(+bias); max over j.
// Wave w owns C tiles (jt in {0,1}) x (mt in {2w, 2w+1}); K=512 in 16 steps.
__global__ __launch_bounds__(256) void k_pool(float* __restrict__ ws)
{
    __shared__ uint_t a1b[32*512/2];   // 32 KB: bf16 [j][k], ushort idx ^= (j&7)<<3
    const int tid = threadIdx.x;
    const int si = blockIdx.x;       // s*32 + i
    const int s  = si >> 5;
    const float* LP = ws + OFF_LP;
    const float4* HP4 = (const float4*)(ws + OFF_HP);
    const float4* A2q = (const float4*)(ws + OFF_A2);   // [2][128] float4

    const float c0 = LP[si*2], c1 = LP[si*2 + 1];

    // ---- phase 1 ----
    for (int idx = tid; idx < 32*128; idx += 256) {
        const int jl = idx >> 7, k4 = idx & 127;
        const int gj = s*32 + jl;
        const float r0 = LP[gj*2] - c0, r1 = LP[gj*2+1] - c1;
        float4 hp = HP4[gj*128 + k4];
        float4 a0 = A2q[k4];
        float4 a1v = A2q[128 + k4];
        float x = fmaxf(hp.x + r0*a0.x + r1*a1v.x, 0.f);
        float y = fmaxf(hp.y + r0*a0.y + r1*a1v.y, 0.f);
        float z = fmaxf(hp.z + r0*a0.z + r1*a1v.z, 0.f);
        float w = fmaxf(hp.w + r0*a0.w + r1*a1v.w, 0.f);
        const int u = (jl*512 + k4*4) ^ ((jl & 7) << 3);   // ushort index, 4-aligned
        uint2 pk;
        pk.x = f2b(x) | (f2b(y) << 16);
        pk.y = f2b(z) | (f2b(w) << 16);
        *(uint2*)&a1b[u >> 1] = pk;
    }
    __syncthreads();

    // ---- phase 2: MFMA ----
    const int lane = tid & 63, w = tid >> 6;     // wave 0..3
    const ushort_t* w2f = (const ushort_t*)(ws + OFF_W2F);
    const ushort_t* a1u = (const ushort_t*)a1b;

    f32x4 acc[2][2];   // [jt][t]
    #pragma unroll
    for (int jt = 0; jt < 2; jt++)
        #pragma unroll
        for (int t = 0; t < 2; t++) acc[jt][t] = (f32x4){0.f,0.f,0.f,0.f};

    const int r0row = (lane & 15), kchunk = (lane >> 4) * 8;
    #pragma unroll 4
    for (int kk = 0; kk < 16; kk++) {
        const int kbase = kk*32 + kchunk;
        // A-frags for jt=0,1: row = jt*16 + (lane&15), 8 bf16 at kbase
        const int ra = r0row, rb2 = 16 + r0row;
        short8v a0 = *(const short8v*)&a1u[(ra *512 + kbase) ^ ((ra  & 7) << 3)];
        short8v a1f= *(const short8v*)&a1u[(rb2*512 + kbase) ^ ((rb2 & 7) << 3)];
        #pragma unroll
        for (int t = 0; t < 2; t++) {
            const int mt = 2*w + t;
            short8v b = *(const short8v*)&w2f[((mt*16 + kk)*64 + lane)*8];
            acc[0][t] = __builtin_amdgcn_mfma_f32_16x16x32_bf16(a0,  b, acc[0][t], 0, 0, 0);
            acc[1][t] = __builtin_amdgcn_mfma_f32_16x16x32_bf16(a1f, b, acc[1][t], 0, 0, 0);
        }
    }

    // ---- reduce: max over j, bias, relu ----
    // C mapping: col = lane&15, row = (lane>>4)*4 + reg  (within 16x16 tile)
    float vt[2];
    #pragma unroll
    for (int t = 0; t < 2; t++) {
        float m0 = fmaxf(fmaxf(acc[0][t][0], acc[0][t][1]), fmaxf(acc[0][t][2], acc[0][t][3]));
        float m1 = fmaxf(fmaxf(acc[1][t][0], acc[1][t][1]), fmaxf(acc[1][t][2], acc[1][t][3]));
        float m = fmaxf(m0, m1);                       // both jt tiles in-wave
        m = fmaxf(m, __shfl_xor(m, 16, 64));
        m = fmaxf(m, __shfl_xor(m, 32, 64));           // now max over all 32 j
        const int col = (2*w + t)*16 + (lane & 15);
        vt[t] = fmaxf(m + ws[F_BP2 + col], 0.f);
    }
    if (lane < 32) {
        const int tl = lane >> 4;
        const int col = (2*w + tl)*16 + (lane & 15);
        ws[OFF_PHP + si*128 + col] = tl ? vt[1] : vt[0];
    }
}

// ---------------- post-pool MLP -> refreshed hidden HC. 4 rows/block ----------------
__global__ __launch_bounds__(256) void k_mlp(float* __restrict__ ws)
{
    __shared__ float dh[4][256];
    __shared__ float m1s[4][1024];
    const int tid = threadIdx.x;
    const int rb  = blockIdx.x * 4;
    const float* HL = ws + OFF_HL; const float* PHP = ws + OFF_PHP; float* HC = ws + OFF_HC;

    #pragma unroll
    for (int r = 0; r < 4; r++) {
        if (tid < 128) dh[r][tid] = HL[(rb+r)*128 + tid];
        else {
            int mm = tid - 128;
            dh[r][128 + mm] = PHP[(rb+r)*128 + mm];
        }
    }
    __syncthreads();

    #pragma unroll
    for (int q = 0; q < 4; q++) {
        const int j = tid + 256*q;
        const float4* w = (const float4*)(ws + F_WM1 + j*256);
        float bb = ws[F_BM1 + j];
        float a0 = bb, a1 = bb, a2 = bb, a3 = bb;
        #pragma unroll 4
        for (int l = 0; l < 64; l++) {
            float4 wv = w[l]; const int e = 4*l;
            float4 d0 = *(const float4*)&dh[0][e];
            float4 d1 = *(const float4*)&dh[1][e];
            float4 d2 = *(const float4*)&dh[2][e];
            float4 d3 = *(const float4*)&dh[3][e];
            a0 += d0.x*wv.x + d0.y*wv.y + d0.z*wv.z + d0.w*wv.w;
            a1 += d1.x*wv.x + d1.y*wv.y + d1.z*wv.z + d1.w*wv.w;
            a2 += d2.x*wv.x + d2.y*wv.y + d2.z*wv.z + d2.w*wv.w;
            a3 += d3.x*wv.x + d3.y*wv.y + d3.z*wv.z + d3.w*wv.w;
        }
        m1s[0][j] = fmaxf(a0, 0.f);
        m1s[1][j] = fmaxf(a1, 0.f);
        m1s[2][j] = fmaxf(a2, 0.f);
        m1s[3][j] = fmaxf(a3, 0.f);
    }
    __syncthreads();

    const int m = tid & 127, half = tid >> 7;
    const float4* w2 = (const float4*)(ws + F_WM2 + m*1024 + half*512);
    float a0 = 0.f, a1 = 0.f, a2 = 0.f, a3 = 0.f;
    #pragma unroll 4
    for (int l = 0; l < 128; l++) {
        float4 wv = w2[l]; const int e = half*512 + 4*l;
        float4 d0 = *(const float4*)&m1s[0][e];
        float4 d1 = *(const float4*)&m1s[1][e];
        float4 d2 = *(const float4*)&m1s[2][e];
        float4 d3 = *(const float4*)&m1s[3][e];
        a0 += d0.x*wv.x + d0.y*wv.y + d0.z*wv.z + d0.w*wv.w;
        a1 += d1.x*wv.x + d1.y*wv.y + d1.z*wv.z + d1.w*wv.w;
        a2 += d2.x*wv.x + d2.y*wv.y + d2.z*wv.z + d2.w*wv.w;
        a3 += d3.x*wv.x + d3.y*wv.y + d3.z*wv.z + d3.w*wv.w;
    }
    if (half == 1) { dh[0][m] = a0; dh[1][m] = a1; dh[2][m] = a2; dh[3][m] = a3; }
    __syncthreads();
    if (half == 0) {
        float bb = ws[F_BM2 + m];
        HC[(rb+0)*128 + m] = fmaxf(a0 + dh[0][m] + bb, 0.f);
        HC[(rb+1)*128 + m] = fmaxf(a1 + dh[1][m] + bb, 0.f);
        HC[(rb+2)*128 + m] = fmaxf(a2 + dh[2][m] + bb, 0.f);
        HC[(rb+3)*128 + m] = fmaxf(a3 + dh[3][m] + bb, 0.f);
    }
}

extern "C" void kernel_launch(void* const* d_in, const int* in_sizes, int n_in,
                              void* d_out, int out_size, void* d_ws, size_t ws_size,
                              hipStream_t stream) {
    float* ws = (float*)d_ws;
    float* out = (float*)d_out;   // reference output dtype is float32

    Ptrs ptrs;   // 22 float tensors, skipping seq_start_end (d_in[4]) and seq_len (d_in[5])
    for (int t = 0; t < 22; t++) ptrs.p[t] = d_in[t < 4 ? t : t + 2];

    k_conv<<<3614, 256, 0, stream>>>(ptrs, ws);   // ceil(925058/256)
    k_init<<<1024, 128, 0, stream>>>(ws);
    k_pre <<<2,    256, 0, stream>>>(ws);
    k_w2f <<<256,  256, 0, stream>>>(ws);

    for (int t = 0; t < T_; t++) {
        k_lstm<<<256, 128, 0, stream>>>(ws, out, t);
        if (t < T_ - 1) {   // last step's pool/MLP would feed a nonexistent step
            k_hp  <<<256,  256, 0, stream>>>(ws);
            k_pool<<<1024, 256, 0, stream>>>(ws);
            k_mlp <<<256,  256, 0, stream>>>(ws);
        }
    }
}

// Round 7
// 672.709 us; speedup vs baseline: 3.0909x; 1.9658x over previous
//
#include <hip/hip_runtime.h>
#include <hip/hip_bf16.h>
#include <math.h>

typedef unsigned short ushort_t;
typedef unsigned int uint_t;

// Problem constants: S=32 scenes, N=32 peds, B=1024, E=64, H=128, PRE=512, MLP_D=1024, T=12
// All float inputs are f32; output is f32.
#define T_ 12

// ---- ws layout (float offsets) ----
#define F_LP0   0         // last_pos      (2048)
#define F_LPR   2048      // last_pos_rel  (2048)
#define F_H0    4096      // h0            (131072)
#define F_C0    135168    // c0            (131072)
#define F_WSP   266240    // Wsp (64,2)
#define F_BSP   266368    // bsp (64)
#define F_WIH   266432    // Wih (512,64)
#define F_WHH   299200    // Whh (512,128)
#define F_BIH   364736
#define F_BHH   365248
#define F_WH2P  365760    // (2,128)
#define F_BH2P  366016    // (2)
#define F_WPE   366032    // (64,2)
#define F_BPE   366160    // (64)
#define F_WP1   366224    // (512,192)
#define F_BP1   464528    // (512)
#define F_WP2   465040    // (128,512)
#define F_BP2   530576    // (128)
#define F_WM1   530704    // (1024,256)
#define F_BM1   792848    // (1024)
#define F_WM2   793872    // (128,1024)
#define F_BM2   924944    // (128)
// State / derived:
#define OFF_HC   925072   // carry hidden (B,128)
#define OFF_HL   1056144  // lstm hidden  (B,128)
#define OFF_C    1187216  // cell         (B,128)
#define OFF_X    1318288  // lstm input   (B,64)
#define OFF_LP   1383824  // positions    (B,2)
#define OFF_HP   1385872  // hp f32 (B,512); ALIASED later each step by Y1 bf16 (1024,1024)
#define OFF_A2   1910160  // (2,512)
#define OFF_B512 1911184  // (512)
#define OFF_W2F  1911696  // Wp2 bf16 B-frag pack (65536 ushorts)
#define OFF_PHP  1977232  // pool max output (B,128)
#define OFF_HPF  2108304  // Wp1b B-frag pack (65536 ushorts = 32768 floats)
#define OFF_M1F  2141072  // Wm1 B-frag pack (262144 ushorts = 131072 floats)
#define OFF_M2F  2272144  // Wm2 B-frag pack (131072 ushorts = 65536 floats)
// total = 2337680 floats = ~9.35 MB of d_ws

typedef __attribute__((ext_vector_type(8))) short short8v;   // 8 bf16 (4 VGPRs)
typedef __attribute__((ext_vector_type(4))) float f32x4;

__device__ __forceinline__ float sigf(float x){ return 1.0f/(1.0f+expf(-x)); }
__device__ __forceinline__ uint_t f2b(float f){  // RNE f32->bf16 (bits in low 16)
    uint_t u = __float_as_uint(f);
    return (u + 0x7FFFu + ((u >> 16) & 1u)) >> 16;
}

struct Ptrs { const void* p[22]; };

// ---------------- copy all f32 inputs into consolidated ws region ----------------
__global__ __launch_bounds__(256) void k_conv(Ptrs ptrs, float* __restrict__ ws)
{
    const int cums[22] = {0,2048,4096,135168,266240,266368,266432,299200,364736,
                          365248,365760,366016,366018,366146,366210,464514,465026,
                          530562,530690,792834,793858,924930};
    const int dof[22]  = {F_LP0,F_LPR,F_H0,F_C0,F_WSP,F_BSP,F_WIH,F_WHH,F_BIH,F_BHH,
                          F_WH2P,F_BH2P,F_WPE,F_BPE,F_WP1,F_BP1,F_WP2,F_BP2,F_WM1,
                          F_BM1,F_WM2,F_BM2};
    const int TOTAL = 925058;
    int g = blockIdx.x*256 + threadIdx.x;
    if (g < TOTAL) {
        int t = 0;
        #pragma unroll
        for (int i = 1; i < 22; i++) t += (g >= cums[i]);
        int li = g - cums[t];
        ws[dof[t] + li] = ((const float*)ptrs.p[t])[li];
    }
}

// ---------------- init: h,c copy; x0 = lpr@Wsp^T+bsp; lp = last_pos ----------------
__global__ __launch_bounds__(128) void k_init(float* __restrict__ ws)
{
    const int b = blockIdx.x, tid = threadIdx.x;
    ws[OFF_HC + b*128 + tid] = ws[F_H0 + b*128 + tid];
    ws[OFF_C  + b*128 + tid] = ws[F_C0 + b*128 + tid];
    if (tid < 64) {
        float p0 = ws[F_LPR + b*2], p1 = ws[F_LPR + b*2 + 1];
        ws[OFF_X + b*64 + tid] = p0*ws[F_WSP + tid*2] + p1*ws[F_WSP + tid*2+1] + ws[F_BSP + tid];
    }
    if (tid < 2) ws[OFF_LP + b*2 + tid] = ws[F_LP0 + b*2 + tid];
}

// ---------------- A2 = Wpe^T@Wp1a^T (2,512); b512 = bp1 + bpe@Wp1a^T ----------------
__global__ __launch_bounds__(256) void k_pre(float* __restrict__ ws)
{
    const int k = blockIdx.x*256 + threadIdx.x;   // 0..511
    float a0 = 0.f, a1 = 0.f, bb = 0.f;
    for (int e = 0; e < 64; e++) {
        float w = ws[F_WP1 + k*192 + e];
        a0 += ws[F_WPE + e*2 + 0] * w;
        a1 += ws[F_WPE + e*2 + 1] * w;
        bb += ws[F_BPE + e]       * w;
    }
    ws[OFF_A2 + k]       = a0;
    ws[OFF_A2 + 512 + k] = a1;
    ws[OFF_B512 + k]     = bb + ws[F_BP1 + k];
}

// ---------------- pack Wp2 into bf16 MFMA B-fragment order (for k_pool) ----------------
__global__ __launch_bounds__(256) void k_w2f(float* __restrict__ ws)
{
    const int idx = blockIdx.x*256 + threadIdx.x;  // 0..65535
    const int i = idx & 7, lane = (idx >> 3) & 63, kk = (idx >> 9) & 15, mt = idx >> 13;
    const int col = mt*16 + (lane & 15);
    const int k   = kk*32 + ((lane >> 4) << 3) + i;
    ushort_t* w2f = (ushort_t*)(ws + OFF_W2F);
    w2f[idx] = (ushort_t)f2b(ws[F_WP2 + col*512 + k]);
}

// ---------------- generic pack: W[n][k] (row-major f32, stride/colOff) -> bf16 B-frags ----------------
__global__ __launch_bounds__(256) void k_pack(float* __restrict__ ws, int srcOff, int stride,
                                              int colOff, int dstOff, int K)
{
    const int idx = blockIdx.x*256 + threadIdx.x;
    const int i = idx & 7, lane = (idx >> 3) & 63;
    const int rest = idx >> 9;
    const int nkk = K >> 5;
    const int kk = rest % nkk, nt = rest / nkk;
    const int n = nt*16 + (lane & 15);
    const int k = kk*32 + ((lane >> 4) << 3) + i;
    ushort_t* dst = (ushort_t*)(ws + dstOff);
    dst[idx] = (ushort_t)f2b(ws[srcOff + n*stride + colOff + k]);
}

// ---------------- MFMA GEMM: C[M x N] = act(A @ W^T + bias) ----------------
// A: f32 [M][K1]+[M][KTOT-K1] (two sources) or bf16 [M][KTOT]; staged to swizzled LDS bf16.
// W: pre-packed bf16 B-frags. Block: ROWS x 128 cols, 4 waves, wave = ROWS/16 x 2 C-tiles.
template<int ROWS, int KTOT, int K1, bool IN_BF16, bool RELU, bool OUT_BF16>
__global__ __launch_bounds__(256) void k_gemm(
    const void* __restrict__ a1src, const void* __restrict__ a2src,
    const ushort_t* __restrict__ wf, const float* __restrict__ bias,
    void* __restrict__ outp, int ldN)
{
    __shared__ ushort_t ab[ROWS*KTOT];
    const int tid = threadIdx.x;
    const int rowBase = blockIdx.x * ROWS;
    const int ntBase  = blockIdx.y * 8;

    // ---- stage A (16B chunks, bf16, XOR-swizzled) ----
    constexpr int CH = KTOT/8;
    for (int idx = tid; idx < ROWS*CH; idx += 256) {
        const int r = idx / CH, k8 = idx - r*CH;
        const int k = k8*8;
        const int grow = rowBase + r;
        uint4 val;
        if (IN_BF16) {
            val = ((const uint4*)a1src)[(grow*KTOT + k) >> 3];
        } else {
            const float* src = (k < K1) ? ((const float*)a1src + grow*K1 + k)
                                        : ((const float*)a2src + grow*(KTOT-K1) + (k-K1));
            float4 f0 = ((const float4*)src)[0];
            float4 f1 = ((const float4*)src)[1];
            val.x = f2b(f0.x) | (f2b(f0.y) << 16);
            val.y = f2b(f0.z) | (f2b(f0.w) << 16);
            val.z = f2b(f1.x) | (f2b(f1.y) << 16);
            val.w = f2b(f1.z) | (f2b(f1.w) << 16);
        }
        const int u = (r*KTOT + k) ^ ((r & 7) << 3);
        *(uint4*)&ab[u] = val;
    }
    __syncthreads();

    // ---- MFMA ----
    const int lane = tid & 63, w = tid >> 6;
    constexpr int NKK = KTOT/32;
    constexpr int NRT = ROWS/16;
    f32x4 acc[NRT][2];
    #pragma unroll
    for (int rt = 0; rt < NRT; rt++)
        #pragma unroll
        for (int ct = 0; ct < 2; ct++) acc[rt][ct] = (f32x4){0.f,0.f,0.f,0.f};

    const int arow = lane & 15, kch = (lane >> 4) * 8;
    #pragma unroll 4
    for (int kk = 0; kk < NKK; kk++) {
        const int kbase = kk*32 + kch;
        short8v afr[NRT];
        #pragma unroll
        for (int rt = 0; rt < NRT; rt++) {
            const int r = rt*16 + arow;
            afr[rt] = *(const short8v*)&ab[(r*KTOT + kbase) ^ ((r & 7) << 3)];
        }
        #pragma unroll
        for (int ct = 0; ct < 2; ct++) {
            const int ntg = ntBase + w*2 + ct;
            short8v b = *(const short8v*)&wf[((ntg*NKK + kk)*64 + lane)*8];
            #pragma unroll
            for (int rt = 0; rt < NRT; rt++)
                acc[rt][ct] = __builtin_amdgcn_mfma_f32_16x16x32_bf16(afr[rt], b, acc[rt][ct], 0, 0, 0);
        }
    }

    // ---- epilogue: bias, act, store. C map: col=lane&15, row=(lane>>4)*4+reg ----
    #pragma unroll
    for (int rt = 0; rt < NRT; rt++) {
        #pragma unroll
        for (int ct = 0; ct < 2; ct++) {
            const int ntg = ntBase + w*2 + ct;
            const int col = ntg*16 + (lane & 15);
            const float bb = bias[col];
            const int rbase = rowBase + rt*16 + ((lane >> 4) << 2);
            #pragma unroll
            for (int reg = 0; reg < 4; reg++) {
                float v = acc[rt][ct][reg] + bb;
                if (RELU) v = fmaxf(v, 0.f);
                if (OUT_BF16) ((ushort_t*)outp)[(rbase+reg)*ldN + col] = (ushort_t)f2b(v);
                else          ((float*)outp)[(rbase+reg)*ldN + col] = v;
            }
        }
    }
}

// ---------------- LSTM step + rel + cur + next x + out (f32). 4 rows/block ----------------
__global__ __launch_bounds__(128) void k_lstm(float* __restrict__ ws,
                                              float* __restrict__ out, int tstep)
{
    __shared__ float xh[4][192];
    __shared__ float h2s[4][128];
    __shared__ float relsh[4][2];
    const int tid = threadIdx.x;
    const int rb  = blockIdx.x * 4;
    float* X  = ws + OFF_X;  float* HC = ws + OFF_HC; float* C = ws + OFF_C;
    float* HL = ws + OFF_HL; float* LP = ws + OFF_LP;

    #pragma unroll
    for (int r = 0; r < 4; r++) {
        if (tid < 64) xh[r][tid] = X[(rb+r)*64 + tid];
        xh[r][64 + tid] = HC[(rb+r)*128 + tid];
    }
    __syncthreads();

    float gacc[4][4];
    #pragma unroll
    for (int q = 0; q < 4; q++) {
        const int j = tid + q*128;
        const float bias = ws[F_BIH + j] + ws[F_BHH + j];
        float a0 = bias, a1 = bias, a2 = bias, a3 = bias;
        const float4* wi = (const float4*)(ws + F_WIH + j*64);
        #pragma unroll 4
        for (int l = 0; l < 16; l++) {
            float4 w = wi[l]; const int e = 4*l;
            a0 += xh[0][e]*w.x + xh[0][e+1]*w.y + xh[0][e+2]*w.z + xh[0][e+3]*w.w;
            a1 += xh[1][e]*w.x + xh[1][e+1]*w.y + xh[1][e+2]*w.z + xh[1][e+3]*w.w;
            a2 += xh[2][e]*w.x + xh[2][e+1]*w.y + xh[2][e+2]*w.z + xh[2][e+3]*w.w;
            a3 += xh[3][e]*w.x + xh[3][e+1]*w.y + xh[3][e+2]*w.z + xh[3][e+3]*w.w;
        }
        const float4* wh = (const float4*)(ws + F_WHH + j*128);
        #pragma unroll 4
        for (int l = 0; l < 32; l++) {
            float4 w = wh[l]; const int e = 64 + 4*l;
            a0 += xh[0][e]*w.x + xh[0][e+1]*w.y + xh[0][e+2]*w.z + xh[0][e+3]*w.w;
            a1 += xh[1][e]*w.x + xh[1][e+1]*w.y + xh[1][e+2]*w.z + xh[1][e+3]*w.w;
            a2 += xh[2][e]*w.x + xh[2][e+1]*w.y + xh[2][e+2]*w.z + xh[2][e+3]*w.w;
            a3 += xh[3][e]*w.x + xh[3][e+1]*w.y + xh[3][e+2]*w.z + xh[3][e+3]*w.w;
        }
        gacc[q][0]=a0; gacc[q][1]=a1; gacc[q][2]=a2; gacc[q][3]=a3;
    }

    #pragma unroll
    for (int r = 0; r < 4; r++) {
        float i_ = sigf(gacc[0][r]);
        float f_ = sigf(gacc[1][r]);
        float g_ = tanhf(gacc[2][r]);
        float o_ = sigf(gacc[3][r]);
        float c2 = f_ * C[(rb+r)*128 + tid] + i_ * g_;
        float h2 = o_ * tanhf(c2);
        C [(rb+r)*128 + tid] = c2;
        HL[(rb+r)*128 + tid] = h2;
        h2s[r][tid] = h2;
    }
    __syncthreads();

    if (tid < 8) {
        int r = tid >> 1, rr = tid & 1;
        float acc = ws[F_BH2P + rr];
        for (int u = 0; u < 128; u++) acc += h2s[r][u] * ws[F_WH2P + rr*128 + u];
        relsh[r][rr] = acc;
        out[tstep*2048 + (rb+r)*2 + rr] = acc;   // f32 output
        LP[(rb+r)*2 + rr] += acc;                // cur = rel + lp
    }
    __syncthreads();

    if (tid < 64) {
        float w0 = ws[F_WSP + tid*2], w1 = ws[F_WSP + tid*2+1], bb = ws[F_BSP + tid];
        #pragma unroll
        for (int r = 0; r < 4; r++)
            X[(rb+r)*64 + tid] = relsh[r][0]*w0 + relsh[r][1]*w1 + bb;
    }
}

// ---------------- MFMA pool layer-2 + max over j. One block per (scene,i). ----------------
__global__ __launch_bounds__(256) void k_pool(float* __restrict__ ws)
{
    __shared__ uint_t a1b[32*512/2];   // 32 KB: bf16 [j][k], ushort idx ^= (j&7)<<3
    const int tid = threadIdx.x;
    const int si = blockIdx.x;       // s*32 + i
    const int s  = si >> 5;
    const float* LP = ws + OFF_LP;
    const float4* HP4 = (const float4*)(ws + OFF_HP);
    const float4* A2q = (const float4*)(ws + OFF_A2);   // [2][128] float4

    const float c0 = LP[si*2], c1 = LP[si*2 + 1];

    // ---- phase 1 ----
    for (int idx = tid; idx < 32*128; idx += 256) {
        const int jl = idx >> 7, k4 = idx & 127;
        const int gj = s*32 + jl;
        const float r0 = LP[gj*2] - c0, r1 = LP[gj*2+1] - c1;
        float4 hp = HP4[gj*128 + k4];
        float4 a0 = A2q[k4];
        float4 a1v = A2q[128 + k4];
        float x = fmaxf(hp.x + r0*a0.x + r1*a1v.x, 0.f);
        float y = fmaxf(hp.y + r0*a0.y + r1*a1v.y, 0.f);
        float z = fmaxf(hp.z + r0*a0.z + r1*a1v.z, 0.f);
        float w = fmaxf(hp.w + r0*a0.w + r1*a1v.w, 0.f);
        const int u = (jl*512 + k4*4) ^ ((jl & 7) << 3);   // ushort index, 4-aligned
        uint2 pk;
        pk.x = f2b(x) | (f2b(y) << 16);
        pk.y = f2b(z) | (f2b(w) << 16);
        *(uint2*)&a1b[u >> 1] = pk;
    }
    __syncthreads();

    // ---- phase 2: MFMA ----
    const int lane = tid & 63, w = tid >> 6;     // wave 0..3
    const ushort_t* w2f = (const ushort_t*)(ws + OFF_W2F);
    const ushort_t* a1u = (const ushort_t*)a1b;

    f32x4 acc[2][2];   // [jt][t]
    #pragma unroll
    for (int jt = 0; jt < 2; jt++)
        #pragma unroll
        for (int t = 0; t < 2; t++) acc[jt][t] = (f32x4){0.f,0.f,0.f,0.f};

    const int r0row = (lane & 15), kchunk = (lane >> 4) * 8;
    #pragma unroll 4
    for (int kk = 0; kk < 16; kk++) {
        const int kbase = kk*32 + kchunk;
        const int ra = r0row, rb2 = 16 + r0row;
        short8v a0 = *(const short8v*)&a1u[(ra *512 + kbase) ^ ((ra  & 7) << 3)];
        short8v a1f= *(const short8v*)&a1u[(rb2*512 + kbase) ^ ((rb2 & 7) << 3)];
        #pragma unroll
        for (int t = 0; t < 2; t++) {
            const int mt = 2*w + t;
            short8v b = *(const short8v*)&w2f[((mt*16 + kk)*64 + lane)*8];
            acc[0][t] = __builtin_amdgcn_mfma_f32_16x16x32_bf16(a0,  b, acc[0][t], 0, 0, 0);
            acc[1][t] = __builtin_amdgcn_mfma_f32_16x16x32_bf16(a1f, b, acc[1][t], 0, 0, 0);
        }
    }

    // ---- reduce: max over j, bias, relu ----
    float vt[2];
    #pragma unroll
    for (int t = 0; t < 2; t++) {
        float m0 = fmaxf(fmaxf(acc[0][t][0], acc[0][t][1]), fmaxf(acc[0][t][2], acc[0][t][3]));
        float m1 = fmaxf(fmaxf(acc[1][t][0], acc[1][t][1]), fmaxf(acc[1][t][2], acc[1][t][3]));
        float m = fmaxf(m0, m1);
        m = fmaxf(m, __shfl_xor(m, 16, 64));
        m = fmaxf(m, __shfl_xor(m, 32, 64));
        const int col = (2*w + t)*16 + (lane & 15);
        vt[t] = fmaxf(m + ws[F_BP2 + col], 0.f);
    }
    if (lane < 32) {
        const int tl = lane >> 4;
        const int col = (2*w + tl)*16 + (lane & 15);
        ws[OFF_PHP + si*128 + col] = tl ? vt[1] : vt[0];
    }
}

extern "C" void kernel_launch(void* const* d_in, const int* in_sizes, int n_in,
                              void* d_out, int out_size, void* d_ws, size_t ws_size,
                              hipStream_t stream) {
    float* ws = (float*)d_ws;
    float* out = (float*)d_out;   // reference output dtype is float32

    Ptrs ptrs;   // 22 float tensors, skipping seq_start_end (d_in[4]) and seq_len (d_in[5])
    for (int t = 0; t < 22; t++) ptrs.p[t] = d_in[t < 4 ? t : t + 2];

    k_conv<<<3614, 256, 0, stream>>>(ptrs, ws);   // ceil(925058/256)
    k_init<<<1024, 128, 0, stream>>>(ws);
    k_pre <<<2,    256, 0, stream>>>(ws);
    k_w2f <<<256,  256, 0, stream>>>(ws);
    // B-fragment packs: Wp1b (512x128, h-cols of Wp1), Wm1 (1024x256), Wm2 (128x1024)
    k_pack<<<256,  256, 0, stream>>>(ws, F_WP1, 192, 64, OFF_HPF, 128);
    k_pack<<<1024, 256, 0, stream>>>(ws, F_WM1, 256, 0,  OFF_M1F, 256);
    k_pack<<<512,  256, 0, stream>>>(ws, F_WM2, 1024, 0, OFF_M2F, 1024);

    const ushort_t* HPF = (const ushort_t*)(ws + OFF_HPF);
    const ushort_t* M1F = (const ushort_t*)(ws + OFF_M1F);
    const ushort_t* M2F = (const ushort_t*)(ws + OFF_M2F);
    void* Y1 = (void*)(ws + OFF_HP);   // bf16 [1024][1024], aliases dead HP

    for (int t = 0; t < T_; t++) {
        k_lstm<<<256, 128, 0, stream>>>(ws, out, t);
        if (t < T_ - 1) {   // last step's pool/MLP would feed a nonexistent step
            // hp: HP[b][n] = HL@Wp1b^T + B512   (no relu, f32 out)
            k_gemm<32,128,128,false,false,false><<<dim3(32,4), 256, 0, stream>>>(
                ws + OFF_HL, nullptr, HPF, ws + OFF_B512, ws + OFF_HP, 512);
            k_pool<<<1024, 256, 0, stream>>>(ws);
            // mlp1: Y1[b][j] = relu([HL|PHP]@Wm1^T + bm1)   (bf16 out)
            k_gemm<32,256,128,false,true,true><<<dim3(32,8), 256, 0, stream>>>(
                ws + OFF_HL, ws + OFF_PHP, M1F, ws + F_BM1, Y1, 1024);
            // mlp2: HC[b][m] = relu(Y1@Wm2^T + bm2)   (f32 out)
            k_gemm<16,1024,1024,true,true,false><<<dim3(64,1), 256, 0, stream>>>(
                Y1, nullptr, M2F, ws + F_BM2, ws + OFF_HC, 128);
        }
    }
}

// Round 8
// 505.358 us; speedup vs baseline: 4.1144x; 1.3312x over previous
//
#include <hip/hip_runtime.h>
#include <hip/hip_bf16.h>
#include <math.h>

typedef unsigned short ushort_t;
typedef unsigned int uint_t;

// Problem constants: S=32 scenes, N=32 peds, B=1024, E=64, H=128, PRE=512, MLP_D=1024, T=12
// All float inputs are f32; output is f32.
#define T_ 12

// ---- ws layout (float offsets) ----
#define F_LP0   0         // last_pos      (2048)
#define F_LPR   2048      // last_pos_rel  (2048)
#define F_H0    4096      // h0            (131072)
#define F_C0    135168    // c0            (131072)
#define F_WSP   266240    // Wsp (64,2)
#define F_BSP   266368    // bsp (64)
#define F_WIH   266432    // Wih (512,64)
#define F_WHH   299200    // Whh (512,128)
#define F_BIH   364736
#define F_BHH   365248
#define F_WH2P  365760    // (2,128)
#define F_BH2P  366016    // (2)
#define F_WPE   366032    // (64,2)
#define F_BPE   366160    // (64)
#define F_WP1   366224    // (512,192)
#define F_BP1   464528    // (512)
#define F_WP2   465040    // (128,512)
#define F_BP2   530576    // (128)
#define F_WM1   530704    // (1024,256)
#define F_BM1   792848    // (1024)
#define F_WM2   793872    // (128,1024)
#define F_BM2   924944    // (128)
// State / derived:
#define OFF_HC   925072   // carry hidden (B,128)
#define OFF_HL   1056144  // lstm hidden  (B,128)
#define OFF_C    1187216  // cell         (B,128)
#define OFF_X    1318288  // lstm input   (B,64)
#define OFF_LP   1383824  // positions    (B,2)
#define OFF_HP   1385872  // hp f32 (B,512)
#define OFF_A2   1910160  // (2,512)
#define OFF_B512 1911184  // (512)
#define OFF_W2F  1911696  // Wp2 bf16 B-frag pack (65536 ushorts)
#define OFF_PHP  1977232  // pool max output (B,128)
#define OFF_HPF  2108304  // Wp1b B-frag pack (65536 ushorts = 32768 floats)
#define OFF_M1F  2141072  // Wm1 B-frag pack (262144 ushorts = 131072 floats)
#define OFF_M2F  2272144  // Wm2 B-frag pack (131072 ushorts = 65536 floats)
#define OFF_BG   2337680  // gate bias bih+bhh (512)
#define OFF_LF   2338192  // Wih|Whh B-frag pack (98304 ushorts = 49152 floats)
// total = 2387344 floats = ~9.55 MB of d_ws

typedef __attribute__((ext_vector_type(8))) short short8v;   // 8 bf16 (4 VGPRs)
typedef __attribute__((ext_vector_type(4))) float f32x4;

__device__ __forceinline__ float sigf(float x){ return 1.0f/(1.0f+expf(-x)); }
__device__ __forceinline__ uint_t f2b(float f){  // RNE f32->bf16 (bits in low 16)
    uint_t u = __float_as_uint(f);
    return (u + 0x7FFFu + ((u >> 16) & 1u)) >> 16;
}

struct Ptrs { const void* p[22]; };

// ---------------- copy all f32 inputs into consolidated ws region ----------------
__global__ __launch_bounds__(256) void k_conv(Ptrs ptrs, float* __restrict__ ws)
{
    const int cums[22] = {0,2048,4096,135168,266240,266368,266432,299200,364736,
                          365248,365760,366016,366018,366146,366210,464514,465026,
                          530562,530690,792834,793858,924930};
    const int dof[22]  = {F_LP0,F_LPR,F_H0,F_C0,F_WSP,F_BSP,F_WIH,F_WHH,F_BIH,F_BHH,
                          F_WH2P,F_BH2P,F_WPE,F_BPE,F_WP1,F_BP1,F_WP2,F_BP2,F_WM1,
                          F_BM1,F_WM2,F_BM2};
    const int TOTAL = 925058;
    int g = blockIdx.x*256 + threadIdx.x;
    if (g < TOTAL) {
        int t = 0;
        #pragma unroll
        for (int i = 1; i < 22; i++) t += (g >= cums[i]);
        int li = g - cums[t];
        ws[dof[t] + li] = ((const float*)ptrs.p[t])[li];
    }
}

// ---------------- init: h,c copy; x0 = lpr@Wsp^T+bsp; lp = last_pos ----------------
__global__ __launch_bounds__(128) void k_init(float* __restrict__ ws)
{
    const int b = blockIdx.x, tid = threadIdx.x;
    ws[OFF_HC + b*128 + tid] = ws[F_H0 + b*128 + tid];
    ws[OFF_C  + b*128 + tid] = ws[F_C0 + b*128 + tid];
    if (tid < 64) {
        float p0 = ws[F_LPR + b*2], p1 = ws[F_LPR + b*2 + 1];
        ws[OFF_X + b*64 + tid] = p0*ws[F_WSP + tid*2] + p1*ws[F_WSP + tid*2+1] + ws[F_BSP + tid];
    }
    if (tid < 2) ws[OFF_LP + b*2 + tid] = ws[F_LP0 + b*2 + tid];
}

// ---------------- A2 = Wpe^T@Wp1a^T (2,512); b512 = bp1 + bpe@Wp1a^T ----------------
__global__ __launch_bounds__(256) void k_pre(float* __restrict__ ws)
{
    const int k = blockIdx.x*256 + threadIdx.x;   // 0..511
    float a0 = 0.f, a1 = 0.f, bb = 0.f;
    for (int e = 0; e < 64; e++) {
        float w = ws[F_WP1 + k*192 + e];
        a0 += ws[F_WPE + e*2 + 0] * w;
        a1 += ws[F_WPE + e*2 + 1] * w;
        bb += ws[F_BPE + e]       * w;
    }
    ws[OFF_A2 + k]       = a0;
    ws[OFF_A2 + 512 + k] = a1;
    ws[OFF_B512 + k]     = bb + ws[F_BP1 + k];
}

// ---------------- gate bias: BG = bih + bhh ----------------
__global__ __launch_bounds__(256) void k_bg(float* __restrict__ ws)
{
    const int k = blockIdx.x*256 + threadIdx.x;   // 0..511
    ws[OFF_BG + k] = ws[F_BIH + k] + ws[F_BHH + k];
}

// ---------------- pack Wp2 into bf16 MFMA B-fragment order (for k_pool) ----------------
__global__ __launch_bounds__(256) void k_w2f(float* __restrict__ ws)
{
    const int idx = blockIdx.x*256 + threadIdx.x;  // 0..65535
    const int i = idx & 7, lane = (idx >> 3) & 63, kk = (idx >> 9) & 15, mt = idx >> 13;
    const int col = mt*16 + (lane & 15);
    const int k   = kk*32 + ((lane >> 4) << 3) + i;
    ushort_t* w2f = (ushort_t*)(ws + OFF_W2F);
    w2f[idx] = (ushort_t)f2b(ws[F_WP2 + col*512 + k]);
}

// ---------------- generic pack: W[n][k] (row-major f32, stride/colOff) -> bf16 B-frags ----------------
__global__ __launch_bounds__(256) void k_pack(float* __restrict__ ws, int srcOff, int stride,
                                              int colOff, int dstOff, int K)
{
    const int idx = blockIdx.x*256 + threadIdx.x;
    const int i = idx & 7, lane = (idx >> 3) & 63;
    const int rest = idx >> 9;
    const int nkk = K >> 5;
    const int kk = rest % nkk, nt = rest / nkk;
    const int n = nt*16 + (lane & 15);
    const int k = kk*32 + ((lane >> 4) << 3) + i;
    ushort_t* dst = (ushort_t*)(ws + dstOff);
    dst[idx] = (ushort_t)f2b(ws[srcOff + n*stride + colOff + k]);
}

// ---------------- pack [Wih|Whh] (512 gates x 192 k) -> bf16 B-frags ----------------
__global__ __launch_bounds__(256) void k_packL(float* __restrict__ ws)
{
    const int idx = blockIdx.x*256 + threadIdx.x;   // 0..98303
    const int i = idx & 7, lane = (idx >> 3) & 63;
    const int rest = idx >> 9;                      // nt*6 + kk
    const int kk = rest % 6, nt = rest / 6;
    const int n = nt*16 + (lane & 15);
    const int k = kk*32 + ((lane >> 4) << 3) + i;
    float v = (k < 64) ? ws[F_WIH + n*64 + k] : ws[F_WHH + n*128 + (k - 64)];
    ushort_t* dst = (ushort_t*)(ws + OFF_LF);
    dst[idx] = (ushort_t)f2b(v);
}

// ---------------- fused LSTM step (MFMA gates) + pointwise + h2p + X refresh + hp GEMM ----
// One block per 32 rows (32 blocks, 256 threads = 4 waves).
__global__ __launch_bounds__(256) void k_lstm2(float* __restrict__ ws,
                                               float* __restrict__ out, int tstep, int do_hp)
{
    __shared__ __align__(16) char smem[65536];
    ushort_t* atile = (ushort_t*)smem;            // [32*192] bf16 swizzled (stage phase)
    float*    gates = (float*)smem;               // [32][512] f32 (gate phase)
    float*    h2s   = (float*)smem;               // [32][128] f32 (post phase)
    ushort_t* h2b   = (ushort_t*)(smem + 16384);  // [32*128] bf16 swizzled
    float*    relsh = (float*)(smem + 24576);     // [32][2]

    const int tid = threadIdx.x;
    const int rb  = blockIdx.x * 32;
    float* X  = ws + OFF_X;  float* HC = ws + OFF_HC; float* C = ws + OFF_C;
    float* HL = ws + OFF_HL; float* LP = ws + OFF_LP;

    // ---- stage A = [X(64) | HC(128)] -> bf16 swizzled ----
    for (int idx = tid; idx < 768; idx += 256) {
        const int r = idx / 24, k8 = idx % 24, k = k8*8, gr = rb + r;
        const float* src = (k < 64) ? (X + gr*64 + k) : (HC + gr*128 + (k - 64));
        float4 f0 = ((const float4*)src)[0];
        float4 f1 = ((const float4*)src)[1];
        uint4 val;
        val.x = f2b(f0.x) | (f2b(f0.y) << 16);
        val.y = f2b(f0.z) | (f2b(f0.w) << 16);
        val.z = f2b(f1.x) | (f2b(f1.y) << 16);
        val.w = f2b(f1.z) | (f2b(f1.w) << 16);
        *(uint4*)&atile[(r*192 + k) ^ ((r & 7) << 3)] = val;
    }
    __syncthreads();

    const int lane = tid & 63, w = tid >> 6;
    const int arow = lane & 15, kch = (lane >> 4) * 8;

    // ---- A-frags to regs (frees LDS for gates) ----
    short8v afr[2][6];
    #pragma unroll
    for (int rt = 0; rt < 2; rt++)
        #pragma unroll
        for (int kk = 0; kk < 6; kk++) {
            const int r = rt*16 + arow;
            afr[rt][kk] = *(const short8v*)&atile[(r*192 + kk*32 + kch) ^ ((r & 7) << 3)];
        }
    __syncthreads();

    // ---- gates MFMA: [32][192] @ [512][192]^T ----
    const ushort_t* LF = (const ushort_t*)(ws + OFF_LF);
    #pragma unroll
    for (int ct = 0; ct < 8; ct++) {
        const int ntg = w*8 + ct;
        f32x4 a0 = (f32x4){0.f,0.f,0.f,0.f}, a1 = (f32x4){0.f,0.f,0.f,0.f};
        #pragma unroll
        for (int kk = 0; kk < 6; kk++) {
            short8v b = *(const short8v*)&LF[((ntg*6 + kk)*64 + lane)*8];
            a0 = __builtin_amdgcn_mfma_f32_16x16x32_bf16(afr[0][kk], b, a0, 0, 0, 0);
            a1 = __builtin_amdgcn_mfma_f32_16x16x32_bf16(afr[1][kk], b, a1, 0, 0, 0);
        }
        const int col = ntg*16 + (lane & 15);
        const float bb = ws[OFF_BG + col];
        const int rb4 = (lane >> 4) << 2;
        #pragma unroll
        for (int reg = 0; reg < 4; reg++) {
            gates[(rb4 + reg)*512 + col]      = a0[reg] + bb;
            gates[(16 + rb4 + reg)*512 + col] = a1[reg] + bb;
        }
    }
    __syncthreads();

    // ---- pointwise: i,f,g,o -> c2, h2 ----
    const int hcol = tid & 127, rhalf = tid >> 7;
    float h2v[16];
    #pragma unroll 4
    for (int rr = 0; rr < 16; rr++) {
        const int r = rhalf*16 + rr, gr = rb + r;
        float gi = gates[r*512 + hcol];
        float gf = gates[r*512 + 128 + hcol];
        float gg = gates[r*512 + 256 + hcol];
        float go = gates[r*512 + 384 + hcol];
        float c2 = sigf(gf) * C[gr*128 + hcol] + sigf(gi) * tanhf(gg);
        float h2 = sigf(go) * tanhf(c2);
        C [gr*128 + hcol] = c2;
        HL[gr*128 + hcol] = h2;
        h2v[rr] = h2;
    }
    __syncthreads();   // all gate reads done; LDS reusable
    #pragma unroll
    for (int rr = 0; rr < 16; rr++) {
        const int r = rhalf*16 + rr;
        h2s[r*128 + hcol] = h2v[rr];
        h2b[(r*128 + hcol) ^ ((r & 7) << 3)] = (ushort_t)f2b(h2v[rr]);
    }
    __syncthreads();

    // ---- h2p: rel = h2 @ Wh2p^T + bh2p; out, LP, relsh ----
    {
        const int r = tid >> 3, rr = (tid >> 2) & 1, sub = tid & 3;
        float a = 0.f;
        #pragma unroll 8
        for (int l = 0; l < 32; l++) {
            const int k = sub*32 + l;
            a += h2s[r*128 + k] * ws[F_WH2P + rr*128 + k];
        }
        a += __shfl_xor(a, 1, 64);
        a += __shfl_xor(a, 2, 64);
        if (sub == 0) {
            const float rel = a + ws[F_BH2P + rr];
            const int gr = rb + r;
            out[tstep*2048 + gr*2 + rr] = rel;
            LP[gr*2 + rr] += rel;
            relsh[r*2 + rr] = rel;
        }
    }
    __syncthreads();

    // ---- X refresh ----
    {
        const int col = tid & 63, rq = tid >> 6;
        const float w0 = ws[F_WSP + col*2], w1 = ws[F_WSP + col*2 + 1], bs = ws[F_BSP + col];
        #pragma unroll
        for (int rr = 0; rr < 8; rr++) {
            const int r = rq*8 + rr;
            X[(rb + r)*64 + col] = relsh[r*2]*w0 + relsh[r*2 + 1]*w1 + bs;
        }
    }

    // ---- hp GEMM: HP = h2 @ Wp1b^T + B512 (A-frags from h2b LDS) ----
    if (do_hp) {
        const ushort_t* HPF = (const ushort_t*)(ws + OFF_HPF);
        float* HP = ws + OFF_HP;
        short8v hf[2][4];
        #pragma unroll
        for (int rt = 0; rt < 2; rt++)
            #pragma unroll
            for (int kk = 0; kk < 4; kk++) {
                const int r = rt*16 + arow;
                hf[rt][kk] = *(const short8v*)&h2b[(r*128 + kk*32 + kch) ^ ((r & 7) << 3)];
            }
        #pragma unroll
        for (int ct = 0; ct < 8; ct++) {
            const int ntg = w*8 + ct;
            f32x4 a0 = (f32x4){0.f,0.f,0.f,0.f}, a1 = (f32x4){0.f,0.f,0.f,0.f};
            #pragma unroll
            for (int kk = 0; kk < 4; kk++) {
                short8v b = *(const short8v*)&HPF[((ntg*4 + kk)*64 + lane)*8];
                a0 = __builtin_amdgcn_mfma_f32_16x16x32_bf16(hf[0][kk], b, a0, 0, 0, 0);
                a1 = __builtin_amdgcn_mfma_f32_16x16x32_bf16(hf[1][kk], b, a1, 0, 0, 0);
            }
            const int col = ntg*16 + (lane & 15);
            const float bb = ws[OFF_B512 + col];
            const int rb4 = (lane >> 4) << 2;
            #pragma unroll
            for (int reg = 0; reg < 4; reg++) {
                HP[(rb + rb4 + reg)*512 + col]      = a0[reg] + bb;
                HP[(rb + 16 + rb4 + reg)*512 + col] = a1[reg] + bb;
            }
        }
    }
}

// ---------------- MFMA pool layer-2 + max over j. One block per (scene,i). ----------------
__global__ __launch_bounds__(256) void k_pool(float* __restrict__ ws)
{
    __shared__ uint_t a1b[32*512/2];   // 32 KB: bf16 [j][k], ushort idx ^= (j&7)<<3
    const int tid = threadIdx.x;
    const int si = blockIdx.x;       // s*32 + i
    const int s  = si >> 5;
    const float* LP = ws + OFF_LP;
    const float4* HP4 = (const float4*)(ws + OFF_HP);
    const float4* A2q = (const float4*)(ws + OFF_A2);   // [2][128] float4

    const float c0 = LP[si*2], c1 = LP[si*2 + 1];

    // ---- phase 1 ----
    for (int idx = tid; idx < 32*128; idx += 256) {
        const int jl = idx >> 7, k4 = idx & 127;
        const int gj = s*32 + jl;
        const float r0 = LP[gj*2] - c0, r1 = LP[gj*2+1] - c1;
        float4 hp = HP4[gj*128 + k4];
        float4 a0 = A2q[k4];
        float4 a1v = A2q[128 + k4];
        float x = fmaxf(hp.x + r0*a0.x + r1*a1v.x, 0.f);
        float y = fmaxf(hp.y + r0*a0.y + r1*a1v.y, 0.f);
        float z = fmaxf(hp.z + r0*a0.z + r1*a1v.z, 0.f);
        float w = fmaxf(hp.w + r0*a0.w + r1*a1v.w, 0.f);
        const int u = (jl*512 + k4*4) ^ ((jl & 7) << 3);   // ushort index, 4-aligned
        uint2 pk;
        pk.x = f2b(x) | (f2b(y) << 16);
        pk.y = f2b(z) | (f2b(w) << 16);
        *(uint2*)&a1b[u >> 1] = pk;
    }
    __syncthreads();

    // ---- phase 2: MFMA ----
    const int lane = tid & 63, w = tid >> 6;     // wave 0..3
    const ushort_t* w2f = (const ushort_t*)(ws + OFF_W2F);
    const ushort_t* a1u = (const ushort_t*)a1b;

    f32x4 acc[2][2];   // [jt][t]
    #pragma unroll
    for (int jt = 0; jt < 2; jt++)
        #pragma unroll
        for (int t = 0; t < 2; t++) acc[jt][t] = (f32x4){0.f,0.f,0.f,0.f};

    const int r0row = (lane & 15), kchunk = (lane >> 4) * 8;
    #pragma unroll 4
    for (int kk = 0; kk < 16; kk++) {
        const int kbase = kk*32 + kchunk;
        const int ra = r0row, rb2 = 16 + r0row;
        short8v a0 = *(const short8v*)&a1u[(ra *512 + kbase) ^ ((ra  & 7) << 3)];
        short8v a1f= *(const short8v*)&a1u[(rb2*512 + kbase) ^ ((rb2 & 7) << 3)];
        #pragma unroll
        for (int t = 0; t < 2; t++) {
            const int mt = 2*w + t;
            short8v b = *(const short8v*)&w2f[((mt*16 + kk)*64 + lane)*8];
            acc[0][t] = __builtin_amdgcn_mfma_f32_16x16x32_bf16(a0,  b, acc[0][t], 0, 0, 0);
            acc[1][t] = __builtin_amdgcn_mfma_f32_16x16x32_bf16(a1f, b, acc[1][t], 0, 0, 0);
        }
    }

    // ---- reduce: max over j, bias, relu ----
    float vt[2];
    #pragma unroll
    for (int t = 0; t < 2; t++) {
        float m0 = fmaxf(fmaxf(acc[0][t][0], acc[0][t][1]), fmaxf(acc[0][t][2], acc[0][t][3]));
        float m1 = fmaxf(fmaxf(acc[1][t][0], acc[1][t][1]), fmaxf(acc[1][t][2], acc[1][t][3]));
        float m = fmaxf(m0, m1);
        m = fmaxf(m, __shfl_xor(m, 16, 64));
        m = fmaxf(m, __shfl_xor(m, 32, 64));
        const int col = (2*w + t)*16 + (lane & 15);
        vt[t] = fmaxf(m + ws[F_BP2 + col], 0.f);
    }
    if (lane < 32) {
        const int tl = lane >> 4;
        const int col = (2*w + tl)*16 + (lane & 15);
        ws[OFF_PHP + si*128 + col] = tl ? vt[1] : vt[0];
    }
}

// ---------------- fused post-pool MLP: HC = relu(relu([HL|PHP]@Wm1^T+bm1)@Wm2^T+bm2) ----
// One block per 16 rows (64 blocks, 256 threads). Y1 lives only in LDS.
__global__ __launch_bounds__(256) void k_mlp12(float* __restrict__ ws)
{
    __shared__ ushort_t at[16*256];    // 8 KB staged A (bf16 swizzled)
    __shared__ ushort_t y1[16*1024];   // 32 KB Y1 (bf16 swizzled)
    const int tid = threadIdx.x;
    const int rb  = blockIdx.x * 16;
    const float* HL = ws + OFF_HL; const float* PHP = ws + OFF_PHP; float* HC = ws + OFF_HC;

    // ---- stage [HL|PHP] ----
    for (int idx = tid; idx < 512; idx += 256) {
        const int r = idx >> 5, k8 = idx & 31, k = k8*8, gr = rb + r;
        const float* src = (k < 128) ? (HL + gr*128 + k) : (PHP + gr*128 + (k - 128));
        float4 f0 = ((const float4*)src)[0];
        float4 f1 = ((const float4*)src)[1];
        uint4 val;
        val.x = f2b(f0.x) | (f2b(f0.y) << 16);
        val.y = f2b(f0.z) | (f2b(f0.w) << 16);
        val.z = f2b(f1.x) | (f2b(f1.y) << 16);
        val.w = f2b(f1.z) | (f2b(f1.w) << 16);
        *(uint4*)&at[(r*256 + k) ^ ((r & 7) << 3)] = val;
    }
    __syncthreads();

    const int lane = tid & 63, w = tid >> 6;
    const int arow = lane & 15, kch = (lane >> 4) * 8;
    const ushort_t* M1F = (const ushort_t*)(ws + OFF_M1F);
    const ushort_t* M2F = (const ushort_t*)(ws + OFF_M2F);

    // ---- A-frags ----
    short8v af[8];
    #pragma unroll
    for (int kk = 0; kk < 8; kk++)
        af[kk] = *(const short8v*)&at[(arow*256 + kk*32 + kch) ^ ((arow & 7) << 3)];

    // ---- mlp1 -> Y1 (LDS) ----
    #pragma unroll 2
    for (int ct = 0; ct < 16; ct++) {
        const int ntg = w*16 + ct;
        f32x4 acc = (f32x4){0.f,0.f,0.f,0.f};
        #pragma unroll
        for (int kk = 0; kk < 8; kk++) {
            short8v b = *(const short8v*)&M1F[((ntg*8 + kk)*64 + lane)*8];
            acc = __builtin_amdgcn_mfma_f32_16x16x32_bf16(af[kk], b, acc, 0, 0, 0);
        }
        const int col = ntg*16 + (lane & 15);
        const float bb = ws[F_BM1 + col];
        const int rb4 = (lane >> 4) << 2;
        #pragma unroll
        for (int reg = 0; reg < 4; reg++) {
            const int rloc = rb4 + reg;
            const float v = fmaxf(acc[reg] + bb, 0.f);
            y1[(rloc*1024 + col) ^ ((rloc & 7) << 3)] = (ushort_t)f2b(v);
        }
    }
    __syncthreads();

    // ---- mlp2 -> HC ----
    f32x4 acc2[2];
    acc2[0] = (f32x4){0.f,0.f,0.f,0.f};
    acc2[1] = (f32x4){0.f,0.f,0.f,0.f};
    #pragma unroll 4
    for (int kk = 0; kk < 32; kk++) {
        short8v a = *(const short8v*)&y1[(arow*1024 + kk*32 + kch) ^ ((arow & 7) << 3)];
        #pragma unroll
        for (int ct = 0; ct < 2; ct++) {
            const int ntg = w*2 + ct;
            short8v b = *(const short8v*)&M2F[((ntg*32 + kk)*64 + lane)*8];
            acc2[ct] = __builtin_amdgcn_mfma_f32_16x16x32_bf16(a, b, acc2[ct], 0, 0, 0);
        }
    }
    #pragma unroll
    for (int ct = 0; ct < 2; ct++) {
        const int ntg = w*2 + ct;
        const int col = ntg*16 + (lane & 15);
        const float bb = ws[F_BM2 + col];
        const int rb4 = (lane >> 4) << 2;
        #pragma unroll
        for (int reg = 0; reg < 4; reg++)
            HC[(rb + rb4 + reg)*128 + col] = fmaxf(acc2[ct][reg] + bb, 0.f);
    }
}

extern "C" void kernel_launch(void* const* d_in, const int* in_sizes, int n_in,
                              void* d_out, int out_size, void* d_ws, size_t ws_size,
                              hipStream_t stream) {
    float* ws = (float*)d_ws;
    float* out = (float*)d_out;   // reference output dtype is float32

    Ptrs ptrs;   // 22 float tensors, skipping seq_start_end (d_in[4]) and seq_len (d_in[5])
    for (int t = 0; t < 22; t++) ptrs.p[t] = d_in[t < 4 ? t : t + 2];

    k_conv <<<3614, 256, 0, stream>>>(ptrs, ws);   // ceil(925058/256)
    k_init <<<1024, 128, 0, stream>>>(ws);
    k_pre  <<<2,    256, 0, stream>>>(ws);
    k_bg   <<<2,    256, 0, stream>>>(ws);
    k_w2f  <<<256,  256, 0, stream>>>(ws);
    k_pack <<<256,  256, 0, stream>>>(ws, F_WP1, 192, 64, OFF_HPF, 128);
    k_pack <<<1024, 256, 0, stream>>>(ws, F_WM1, 256, 0,  OFF_M1F, 256);
    k_pack <<<512,  256, 0, stream>>>(ws, F_WM2, 1024, 0, OFF_M2F, 1024);
    k_packL<<<384,  256, 0, stream>>>(ws);

    for (int t = 0; t < T_; t++) {
        k_lstm2<<<32, 256, 0, stream>>>(ws, out, t, (t < T_ - 1) ? 1 : 0);
        if (t < T_ - 1) {   // last step's pool/MLP would feed a nonexistent step
            k_pool <<<1024, 256, 0, stream>>>(ws);
            k_mlp12<<<64,   256, 0, stream>>>(ws);
        }
    }
}